// Round 3
// baseline (626.040 us; speedup 1.0000x reference)
//
#include <hip/hip_runtime.h>

typedef __bf16 bf16_t;
typedef __bf16 bf16x8 __attribute__((ext_vector_type(8)));
typedef __bf16 bf16x4 __attribute__((ext_vector_type(4)));
typedef float  f32x4  __attribute__((ext_vector_type(4)));

#define DEVINL __device__ __forceinline__

// ---------------- per-batch workspace layout (bytes) ----------------
// Peak ~189.1 MB; batches processed sequentially.
static constexpr size_t OFF_QKV = 0;                                  // qkv f32 [1536][16384]
static constexpr size_t SZ_QKV  = (size_t)1536 * 16384 * 4;           // 100,663,296
static constexpr size_t OFF_Y   = OFF_QKV + SZ_QKV;                   // y bf16 [1536][16384]
static constexpr size_t SZ_Y    = (size_t)1536 * 16384 * 2;           // 50,331,648
static constexpr size_t OFF_ATT = OFF_Y + SZ_Y;                       // attT bf16 [16384][1024]; xT_hi/xT_lo aliased here
static constexpr size_t SZ_ATT  = (size_t)16384 * 1024 * 2;           // 33,554,432
static constexpr size_t OFF_XTH = OFF_ATT;                            // xT_hi bf16 [16384][512] (dead after K1)
static constexpr size_t OFF_XTL = OFF_ATT + (size_t)16384 * 512 * 2;  // xT_lo bf16 [16384][512]
static constexpr size_t OFF_WQH = OFF_ATT + SZ_ATT;                   // wq_hi bf16 [1536][512]
static constexpr size_t SZ_WQ   = (size_t)1536 * 512 * 2;
static constexpr size_t OFF_WQL = OFF_WQH + SZ_WQ;                    // wq_lo bf16
static constexpr size_t OFF_WP  = OFF_WQL + SZ_WQ;                    // w_proj bf16 [512][1024]
static constexpr size_t SZ_WP   = (size_t)512 * 1024 * 2;
static constexpr size_t OFF_VK  = OFF_WP + SZ_WP;                     // vk f32 [128][72]
static constexpr size_t SZ_VK   = (size_t)128 * 72 * 4;
static constexpr size_t OFF_VKP = OFF_VK + SZ_VK;                     // vk partials f32 [128][8][72]
static constexpr size_t SZ_VKP  = (size_t)128 * 8 * 72 * 4;
static constexpr size_t OFF_BNI = OFF_VKP + SZ_VKP;                   // f32[512]
static constexpr size_t OFF_BNA = OFF_BNI + 2048;                     // f32[512]
static constexpr size_t WS_NEEDED = OFF_BNA + 2048;                   // ~189.1 MB

// ---------------- helpers ----------------
DEVINL void gload16(const bf16_t* g, bf16_t* l) {
  // async global->LDS, 16B per lane; LDS dest = wave-uniform base + lane*16
  __builtin_amdgcn_global_load_lds((const __attribute__((address_space(1))) void*)g,
                                   (__attribute__((address_space(3))) void*)l, 16, 0, 0);
}

// ---------------- K0a: transpose x (f32 [512][16384]) -> xT_hi/xT_lo (bf16 [16384][512]) ----------------
__global__ __launch_bounds__(256)
void xpose_kernel(const float* __restrict__ x, bf16_t* __restrict__ xTh, bf16_t* __restrict__ xTl) {
  __shared__ float t[32][33];
  const int n0 = blockIdx.x * 32, c0 = blockIdx.y * 32;
  const int tx = threadIdx.x & 31, ty = threadIdx.x >> 5;  // ty 0..7
#pragma unroll
  for (int r = 0; r < 4; ++r)
    t[ty + r * 8][tx] = x[(size_t)(c0 + ty + r * 8) * 16384 + n0 + tx];
  __syncthreads();
#pragma unroll
  for (int r = 0; r < 4; ++r) {
    const float v = t[tx][ty + r * 8];
    const bf16_t hi = (bf16_t)v;
    const bf16_t lo = (bf16_t)(v - (float)hi);
    const size_t o = (size_t)(n0 + ty + r * 8) * 512 + c0 + tx;
    xTh[o] = hi; xTl[o] = lo;
  }
}

// ---------------- K0b: split weights to bf16 hi/lo, fold BN ----------------
__global__ __launch_bounds__(256)
void prep_kernel(const float* __restrict__ wq, const float* __restrict__ wp,
                 const float* __restrict__ gam, const float* __restrict__ bet,
                 const float* __restrict__ mu, const float* __restrict__ va,
                 bf16_t* __restrict__ wqh, bf16_t* __restrict__ wql, bf16_t* __restrict__ wpb,
                 float* __restrict__ bni, float* __restrict__ bna) {
  const int i = blockIdx.x * 256 + threadIdx.x;
  if (i < 1536 * 512) {
    const float v = wq[i];
    const bf16_t hi = (bf16_t)v;
    wqh[i] = hi; wql[i] = (bf16_t)(v - (float)hi);
  }
  const int j = i - 1536 * 512;
  if (j >= 0 && j < 512 * 1024) wpb[j] = (bf16_t)wp[j];
  const int k = i - (1536 * 512 + 512 * 1024);
  if (k >= 0 && k < 512) {
    float inv = gam[k] / sqrtf(va[k] + 1e-5f);
    bni[k] = inv;
    bna[k] = bet[k] - mu[k] * inv;
  }
}

// ---------------- K1: split-precision GEMM: C_f32[M][N] = (Ah+Al)[M][K] * (Bh+Bl)[N][K]^T ----------------
// 128x128 tile, BK=32, 256 threads; 4 MFMA chains (hh, hl, lh, ll) -> ~f32 accuracy
__global__ __launch_bounds__(256, 2)
void gemm_split_kernel(const bf16_t* __restrict__ Ah, const bf16_t* __restrict__ Al,
                       const bf16_t* __restrict__ Bh, const bf16_t* __restrict__ Bl,
                       float* __restrict__ C, const int M, const int N, const int K) {
  __shared__ __align__(16) bf16_t AsH[128 * 32];
  __shared__ __align__(16) bf16_t AsL[128 * 32];
  __shared__ __align__(16) bf16_t BsH[128 * 32];
  __shared__ __align__(16) bf16_t BsL[128 * 32];
  const int tid  = threadIdx.x;
  const int m0   = blockIdx.y * 128, n0 = blockIdx.x * 128;
  const int wid  = tid >> 6;
  const int lane = tid & 63;
  const int fr   = lane & 15, fg = lane >> 4;
  const int wm   = (wid >> 1) * 64, wn = (wid & 1) * 64;
  const size_t aoff = (size_t)m0 * K, boff = (size_t)n0 * K;
  const int srow = tid >> 2;        // 0..63
  const int soff = (tid & 3) * 8;
  bf16_t* lAH = AsH + (size_t)wid * 16 * 32;
  bf16_t* lAL = AsL + (size_t)wid * 16 * 32;
  bf16_t* lBH = BsH + (size_t)wid * 16 * 32;
  bf16_t* lBL = BsL + (size_t)wid * 16 * 32;

  f32x4 acc[4][4] = {};

  for (int kk = 0; kk < K; kk += 32) {
    __syncthreads();
    const size_t g0 = (size_t)srow * K + kk + soff;
    const size_t g1 = (size_t)(srow + 64) * K + kk + soff;
    gload16(Ah + aoff + g0, lAH);
    gload16(Ah + aoff + g1, lAH + 64 * 32);
    gload16(Al + aoff + g0, lAL);
    gload16(Al + aoff + g1, lAL + 64 * 32);
    gload16(Bh + boff + g0, lBH);
    gload16(Bh + boff + g1, lBH + 64 * 32);
    gload16(Bl + boff + g0, lBL);
    gload16(Bl + boff + g1, lBL + 64 * 32);
    __syncthreads();
    bf16x8 ah[4], al[4], bh[4], bl[4];
#pragma unroll
    for (int i = 0; i < 4; ++i) {
      const int ra = (wm + i * 16 + fr) * 32 + fg * 8;
      ah[i] = *(const bf16x8*)&AsH[ra];
      al[i] = *(const bf16x8*)&AsL[ra];
      const int rb = (wn + i * 16 + fr) * 32 + fg * 8;
      bh[i] = *(const bf16x8*)&BsH[rb];
      bl[i] = *(const bf16x8*)&BsL[rb];
    }
#pragma unroll
    for (int i = 0; i < 4; ++i)
#pragma unroll
      for (int j = 0; j < 4; ++j) {
        acc[i][j] = __builtin_amdgcn_mfma_f32_16x16x32_bf16(ah[i], bh[j], acc[i][j], 0, 0, 0);
        acc[i][j] = __builtin_amdgcn_mfma_f32_16x16x32_bf16(ah[i], bl[j], acc[i][j], 0, 0, 0);
        acc[i][j] = __builtin_amdgcn_mfma_f32_16x16x32_bf16(al[i], bh[j], acc[i][j], 0, 0, 0);
        acc[i][j] = __builtin_amdgcn_mfma_f32_16x16x32_bf16(al[i], bl[j], acc[i][j], 0, 0, 0);
      }
  }

#pragma unroll
  for (int i = 0; i < 4; ++i)
#pragma unroll
    for (int r = 0; r < 4; ++r) {
      const int m = m0 + wm + i * 16 + fg * 4 + r;
#pragma unroll
      for (int j = 0; j < 4; ++j) {
        const int n = n0 + wn + j * 16 + fr;
        C[(size_t)m * N + n] = acc[i][j][r];
      }
    }
}

// ---------------- K5: plain bf16 GEMM with BN epilogue: out_f32 = A[M][K]*B[N][K]^T ----------------
__global__ __launch_bounds__(256, 2)
void gemm_bt_kernel(const bf16_t* __restrict__ A, const bf16_t* __restrict__ B,
                    float* __restrict__ Cout, const int M, const int N, const int K,
                    const float* __restrict__ bni, const float* __restrict__ bna) {
  __shared__ __align__(16) bf16_t As[128 * 32];
  __shared__ __align__(16) bf16_t Bs[128 * 32];
  const int tid  = threadIdx.x;
  const int m0   = blockIdx.y * 128, n0 = blockIdx.x * 128;
  const int wid  = tid >> 6;
  const int lane = tid & 63;
  const int fr   = lane & 15, fg = lane >> 4;
  const int wm   = (wid >> 1) * 64, wn = (wid & 1) * 64;
  const bf16_t* Ab = A + (size_t)m0 * K;
  const bf16_t* Bb = B + (size_t)n0 * K;
  const int srow = tid >> 2;
  const int soff = (tid & 3) * 8;
  bf16_t* lA = As + (size_t)wid * 16 * 32;
  bf16_t* lB = Bs + (size_t)wid * 16 * 32;

  f32x4 acc[4][4] = {};

  for (int kk = 0; kk < K; kk += 32) {
    __syncthreads();
    gload16(Ab + (size_t)srow * K + kk + soff,        lA);
    gload16(Ab + (size_t)(srow + 64) * K + kk + soff, lA + 64 * 32);
    gload16(Bb + (size_t)srow * K + kk + soff,        lB);
    gload16(Bb + (size_t)(srow + 64) * K + kk + soff, lB + 64 * 32);
    __syncthreads();
    bf16x8 af[4], bfr[4];
#pragma unroll
    for (int i = 0; i < 4; ++i) af[i]  = *(const bf16x8*)&As[(wm + i * 16 + fr) * 32 + fg * 8];
#pragma unroll
    for (int j = 0; j < 4; ++j) bfr[j] = *(const bf16x8*)&Bs[(wn + j * 16 + fr) * 32 + fg * 8];
#pragma unroll
    for (int i = 0; i < 4; ++i)
#pragma unroll
      for (int j = 0; j < 4; ++j)
        acc[i][j] = __builtin_amdgcn_mfma_f32_16x16x32_bf16(af[i], bfr[j], acc[i][j], 0, 0, 0);
  }

#pragma unroll
  for (int i = 0; i < 4; ++i)
#pragma unroll
    for (int r = 0; r < 4; ++r) {
      const int m = m0 + wm + i * 16 + fg * 4 + r;
      const float sc = bni[m], sh = bna[m];
#pragma unroll
      for (int j = 0; j < 4; ++j) {
        const int n = n0 + wn + j * 16 + fr;
        Cout[(size_t)m * N + n] = acc[i][j][r] * sc + sh;
      }
    }
}

// ---------------- K2: fused depthwise 5x5 (pad 2) + grouped 1x1 (8->8), f32 in, bf16 out ----------------
__global__ __launch_bounds__(256)
void dwpw_kernel(const float* __restrict__ qkv, const float* __restrict__ wdw,
                 const float* __restrict__ wpw, bf16_t* __restrict__ y) {
  const int g = blockIdx.y, t = blockIdx.x;
  const int ty0 = (t >> 2) * 32, tx0 = (t & 3) * 32;
  const int tid = threadIdx.x;
  __shared__ __align__(16) float sin_[8][36][36];
  __shared__ float swd[8][25];
  __shared__ float swp[8][8];
  if (tid < 200) swd[tid / 25][tid % 25] = wdw[(g * 8 + tid / 25) * 25 + tid % 25];
  if (tid < 64)  swp[tid >> 3][tid & 7] = wpw[(g * 8 + (tid >> 3)) * 8 + (tid & 7)];
  const size_t cbase = (size_t)g * 8 * 16384;
  for (int idx = tid; idx < 8 * 36 * 36; idx += 256) {
    const int ch = idx / 1296, rem = idx % 1296, r = rem / 36, cc = rem % 36;
    const int iy = ty0 + r - 2, ix = tx0 + cc - 2;
    float v = 0.f;
    if ((unsigned)iy < 128u && (unsigned)ix < 128u)
      v = qkv[cbase + (size_t)ch * 16384 + iy * 128 + ix];
    sin_[ch][r][cc] = v;
  }
  __syncthreads();
  const int px = (tid & 7) * 4, py = tid >> 3;
  float dwres[8][4];
#pragma unroll
  for (int ch = 0; ch < 8; ++ch) {
    float o0 = 0.f, o1 = 0.f, o2 = 0.f, o3 = 0.f;
#pragma unroll
    for (int di = 0; di < 5; ++di) {
      f32x4 va0 = *(const f32x4*)&sin_[ch][py + di][px];
      f32x4 va1 = *(const f32x4*)&sin_[ch][py + di][px + 4];
      float vv[8] = {va0[0], va0[1], va0[2], va0[3], va1[0], va1[1], va1[2], va1[3]};
#pragma unroll
      for (int dj = 0; dj < 5; ++dj) {
        const float w = swd[ch][di * 5 + dj];
        o0 += vv[dj + 0] * w; o1 += vv[dj + 1] * w; o2 += vv[dj + 2] * w; o3 += vv[dj + 3] * w;
      }
    }
    dwres[ch][0] = o0; dwres[ch][1] = o1; dwres[ch][2] = o2; dwres[ch][3] = o3;
  }
#pragma unroll
  for (int oc = 0; oc < 8; ++oc) {
    float o[4] = {0.f, 0.f, 0.f, 0.f};
#pragma unroll
    for (int ic = 0; ic < 8; ++ic) {
      const float w = swp[oc][ic];
#pragma unroll
      for (int u = 0; u < 4; ++u) o[u] += dwres[ic][u] * w;
    }
    bf16x4 ov;
#pragma unroll
    for (int u = 0; u < 4; ++u) ov[u] = (bf16_t)o[u];
    *(bf16x4*)&y[cbase + (size_t)oc * 16384 + (ty0 + py) * 128 + tx0 + px] = ov;
  }
}

// ---------------- K3a: per-slice partial vk[d][e] = sum_n v_d * relu(k_e) (+ k-sum row) ----------------
__global__ __launch_bounds__(256)
void vk_partial_kernel(const float* __restrict__ qkv, const bf16_t* __restrict__ yb,
                       float* __restrict__ part) {
  const int h = blockIdx.y, s = blockIdx.x;  // s: 0..7 pixel slices
  const bool useY = h >= 64;
  const float*  srcF = qkv + (size_t)24 * h * 16384;
  const bf16_t* srcB = yb + (size_t)24 * (h & 63) * 16384;
  float a[8][8] = {};
  float ak[8] = {};
  const int base = s * 2048 + (int)threadIdx.x;
  for (int it = 0; it < 8; ++it) {
    const int p = base + it * 256;
    float kv[8], vv[8];
#pragma unroll
    for (int e = 0; e < 8; ++e) {
      const float raw = useY ? (float)srcB[(size_t)(8 + e) * 16384 + p]
                             : srcF[(size_t)(8 + e) * 16384 + p];
      kv[e] = fmaxf(0.f, raw);
    }
#pragma unroll
    for (int d = 0; d < 8; ++d)
      vv[d] = useY ? (float)srcB[(size_t)(16 + d) * 16384 + p]
                   : srcF[(size_t)(16 + d) * 16384 + p];
#pragma unroll
    for (int d = 0; d < 8; ++d)
#pragma unroll
      for (int e = 0; e < 8; ++e) a[d][e] += vv[d] * kv[e];
#pragma unroll
    for (int e = 0; e < 8; ++e) ak[e] += kv[e];
  }
  __shared__ float red[4][72];
  const int lane = threadIdx.x & 63, wid = threadIdx.x >> 6;
#pragma unroll
  for (int i = 0; i < 72; ++i) {
    float v = (i < 64) ? a[i >> 3][i & 7] : ak[i - 64];
    v += __shfl_xor(v, 32); v += __shfl_xor(v, 16); v += __shfl_xor(v, 8);
    v += __shfl_xor(v, 4);  v += __shfl_xor(v, 2);  v += __shfl_xor(v, 1);
    if (lane == 0) red[wid][i] = v;
  }
  __syncthreads();
  if (threadIdx.x < 72) {
    const float sum_ = red[0][threadIdx.x] + red[1][threadIdx.x] + red[2][threadIdx.x] + red[3][threadIdx.x];
    part[((size_t)h * 8 + s) * 72 + threadIdx.x] = sum_;
  }
}

// ---------------- K3b: deterministic reduce of 8 slices ----------------
__global__ __launch_bounds__(128)
void vk_reduce_kernel(const float* __restrict__ part, float* __restrict__ vk) {
  const int h = blockIdx.x;  // 0..127
  const int i = threadIdx.x;
  if (i < 72) {
    float s = 0.f;
#pragma unroll
    for (int t = 0; t < 8; ++t) s += part[((size_t)h * 8 + t) * 72 + i];
    vk[(size_t)h * 72 + i] = s;
  }
}

// ---------------- K4: attention apply -> attT bf16 [16384][1024] ----------------
__global__ __launch_bounds__(256)
void attn_kernel(const float* __restrict__ qkv, const bf16_t* __restrict__ yb,
                 const float* __restrict__ vk, bf16_t* __restrict__ attT) {
  const int n0 = blockIdx.x * 32;
  const int tid = threadIdx.x;
  const int px = tid & 31, hl = tid >> 5;  // hl: 0..7
  __shared__ __align__(16) bf16_t att_s[32 * 512];
  __shared__ float vk_s[576];
  for (int grp = 0; grp < 2; ++grp) {
    for (int hg = 0; hg < 8; ++hg) {
      __syncthreads();  // protect vk_s (and att_s on grp switch)
      for (int i = tid; i < 576; i += 256)
        vk_s[i] = vk[((size_t)grp * 64 + hg * 8) * 72 + i];
      __syncthreads();
      const int hh = hg * 8 + hl;  // head within half (0..63)
      float q[8];
      if (grp == 0) {
        const float* plane = qkv + (size_t)(24 * hh) * 16384 + n0 + px;
#pragma unroll
        for (int e = 0; e < 8; ++e) q[e] = fmaxf(0.f, plane[(size_t)e * 16384]);
      } else {
        const bf16_t* plane = yb + (size_t)(24 * hh) * 16384 + n0 + px;
#pragma unroll
        for (int e = 0; e < 8; ++e) q[e] = fmaxf(0.f, (float)plane[(size_t)e * 16384]);
      }
      float den = 1e-15f;
#pragma unroll
      for (int e = 0; e < 8; ++e) den += vk_s[hl * 72 + 64 + e] * q[e];
      const float rden = 1.0f / den;
      bf16x8 r8;
#pragma unroll
      for (int d = 0; d < 8; ++d) {
        float num = 0.f;
#pragma unroll
        for (int e = 0; e < 8; ++e) num += vk_s[hl * 72 + d * 8 + e] * q[e];
        r8[d] = (bf16_t)(num * rden);
      }
      const int chunk = hg * 8 + hl;  // 16B chunk index within half-row
      *(bf16x8*)&att_s[px * 512 + ((chunk ^ (px & 7)) << 3)] = r8;
    }
    __syncthreads();
    bf16_t* dst = attT + (size_t)n0 * 1024 + grp * 512;
    for (int i = tid; i < 2048; i += 256) {
      const int r = i >> 6, cc = i & 63;
      bf16x8 v = *(const bf16x8*)&att_s[r * 512 + (((cc ^ (r & 7))) << 3)];
      *(bf16x8*)&dst[(size_t)r * 1024 + cc * 8] = v;
    }
  }
}

// ---------------- launch ----------------
extern "C" void kernel_launch(void* const* d_in, const int* in_sizes, int n_in,
                              void* d_out, int out_size, void* d_ws, size_t ws_size,
                              hipStream_t stream) {
  if (ws_size < WS_NEEDED) return;  // need ~189.1 MB scratch
  const float* x      = (const float*)d_in[0];
  const float* w_qkv  = (const float*)d_in[1];
  const float* w_dw   = (const float*)d_in[2];
  const float* w_pw   = (const float*)d_in[3];
  const float* w_proj = (const float*)d_in[4];
  const float* gam    = (const float*)d_in[5];
  const float* bet    = (const float*)d_in[6];
  const float* mu     = (const float*)d_in[7];
  const float* va     = (const float*)d_in[8];

  char* w = (char*)d_ws;
  float*  qkv  = (float*)(w + OFF_QKV);
  bf16_t* yb   = (bf16_t*)(w + OFF_Y);
  bf16_t* xTh  = (bf16_t*)(w + OFF_XTH);  // aliased with attT (dead after K1)
  bf16_t* xTl  = (bf16_t*)(w + OFF_XTL);
  bf16_t* attT = (bf16_t*)(w + OFF_ATT);
  bf16_t* wqh  = (bf16_t*)(w + OFF_WQH);
  bf16_t* wql  = (bf16_t*)(w + OFF_WQL);
  bf16_t* wpb  = (bf16_t*)(w + OFF_WP);
  float*  vk   = (float*)(w + OFF_VK);
  float*  part = (float*)(w + OFF_VKP);
  float*  bni  = (float*)(w + OFF_BNI);
  float*  bna  = (float*)(w + OFF_BNA);

  dim3 blk(256);
  // weights + BN fold (once)
  prep_kernel<<<dim3((1536 * 512 + 512 * 1024 + 512 + 255) / 256), blk, 0, stream>>>(
      w_qkv, w_proj, gam, bet, mu, va, wqh, wql, wpb, bni, bna);

  for (int b = 0; b < 2; ++b) {
    const float* xb = x + (size_t)b * 512 * 16384;
    float* outb = (float*)d_out + (size_t)b * 512 * 16384;
    // K0a: x -> xT hi/lo bf16
    xpose_kernel<<<dim3(512, 16), blk, 0, stream>>>(xb, xTh, xTl);
    // K1: qkv = w_qkv * x  (M=1536, N=16384, K=512), split-precision, f32 out
    gemm_split_kernel<<<dim3(128, 12), blk, 0, stream>>>(
        wqh, wql, xTh, xTl, qkv, 1536, 16384, 512);
    // K2: fused dw 5x5 + grouped pw (f32 in, bf16 out)
    dwpw_kernel<<<dim3(16, 192), blk, 0, stream>>>(qkv, w_dw, w_pw, yb);
    // K3: vk accumulation (partials, then deterministic reduce)
    vk_partial_kernel<<<dim3(8, 128), blk, 0, stream>>>(qkv, yb, part);
    vk_reduce_kernel<<<dim3(128), dim3(128), 0, stream>>>(part, vk);
    // K4: attention apply -> attT
    attn_kernel<<<dim3(512), blk, 0, stream>>>(qkv, yb, vk, attT);
    // K5: out = w_proj * att + BN  (M=512, N=16384, K=1024), f32 out
    gemm_bt_kernel<<<dim3(128, 4), blk, 0, stream>>>(
        wpb, attT, outb, 512, 16384, 1024, bni, bna);
  }
}

// Round 4
// 451.612 us; speedup vs baseline: 1.3862x; 1.3862x over previous
//
#include <hip/hip_runtime.h>

typedef __bf16 bf16_t;
typedef __bf16 bf16x8 __attribute__((ext_vector_type(8)));
typedef __bf16 bf16x4 __attribute__((ext_vector_type(4)));
typedef __bf16 bf16x2 __attribute__((ext_vector_type(2)));
typedef float  f32x4  __attribute__((ext_vector_type(4)));

#define DEVINL __device__ __forceinline__

// ---------------- per-batch workspace layout (bytes) ----------------
static constexpr size_t N_PIX  = 16384;
static constexpr size_t OFF_Q   = 0;                                   // Q f32 [512][N]
static constexpr size_t SZ_Q    = (size_t)512 * N_PIX * 4;             // 33.55 MB
static constexpr size_t OFF_KV  = OFF_Q + SZ_Q;                        // KV bf16 [1024][N]: rows 0..511 K, 512..1023 V
static constexpr size_t SZ_KV   = (size_t)1024 * N_PIX * 2;            // 33.55 MB
static constexpr size_t OFF_Y   = OFF_KV + SZ_KV;                      // y bf16 [1536][N] (interleaved channels)
static constexpr size_t SZ_Y    = (size_t)1536 * N_PIX * 2;            // 50.33 MB
static constexpr size_t OFF_ATT = OFF_Y + SZ_Y;                        // attT bf16 [N][1024]; xTh/xTl aliased
static constexpr size_t SZ_ATT  = (size_t)N_PIX * 1024 * 2;            // 33.55 MB
static constexpr size_t OFF_XTH = OFF_ATT;                             // xT_hi bf16 [N][512] (dead after GEMMs)
static constexpr size_t OFF_XTL = OFF_ATT + (size_t)N_PIX * 512 * 2;   // xT_lo bf16 [N][512]
static constexpr size_t OFF_WQH = OFF_ATT + SZ_ATT;                    // wq_hi bf16 [512][512]
static constexpr size_t SZ_WQ   = (size_t)512 * 512 * 2;
static constexpr size_t OFF_WQL = OFF_WQH + SZ_WQ;
static constexpr size_t OFF_WKV = OFF_WQL + SZ_WQ;                     // wkv bf16 [1024][512]
static constexpr size_t SZ_WKV  = (size_t)1024 * 512 * 2;
static constexpr size_t OFF_WP  = OFF_WKV + SZ_WKV;                    // w_proj bf16 [512][1024]
static constexpr size_t SZ_WP   = (size_t)512 * 1024 * 2;
static constexpr size_t OFF_VK  = OFF_WP + SZ_WP;                      // vk f32 [128][72]
static constexpr size_t SZ_VK   = (size_t)128 * 72 * 4;
static constexpr size_t OFF_VKP = OFF_VK + SZ_VK;                      // vk partials f32 [128][8][72]
static constexpr size_t SZ_VKP  = (size_t)128 * 8 * 72 * 4;
static constexpr size_t OFF_BNI = OFF_VKP + SZ_VKP;                    // f32[512]
static constexpr size_t OFF_BNA = OFF_BNI + 2048;                      // f32[512]
static constexpr size_t WS_NEEDED = OFF_BNA + 2048;                    // ~154.5 MB

// ---------------- helpers ----------------
DEVINL void gload16(const bf16_t* g, bf16_t* l) {
  // async global->LDS, 16B per lane; LDS dest = wave-uniform base + lane*16
  __builtin_amdgcn_global_load_lds((const __attribute__((address_space(1))) void*)g,
                                   (__attribute__((address_space(3))) void*)l, 16, 0, 0);
}

// ---------------- K0a: transpose x (f32 [512][N]) -> xT_hi/xT_lo (bf16 [N][512]) ----------------
__global__ __launch_bounds__(256)
void xpose_kernel(const float* __restrict__ x, bf16_t* __restrict__ xTh, bf16_t* __restrict__ xTl) {
  __shared__ float t[32][33];
  const int n0 = blockIdx.x * 32, c0 = blockIdx.y * 32;
  const int tx = threadIdx.x & 31, ty = threadIdx.x >> 5;  // ty 0..7
#pragma unroll
  for (int r = 0; r < 4; ++r)
    t[ty + r * 8][tx] = x[(size_t)(c0 + ty + r * 8) * N_PIX + n0 + tx];
  __syncthreads();
#pragma unroll
  for (int r = 0; r < 4; ++r) {
    const float v = t[tx][ty + r * 8];
    const bf16_t hi = (bf16_t)v;
    const bf16_t lo = (bf16_t)(v - (float)hi);
    const size_t o = (size_t)(n0 + ty + r * 8) * 512 + c0 + tx;
    xTh[o] = hi; xTl[o] = lo;
  }
}

// ---------------- K0b: reorder+split weights, fold BN ----------------
// w_qkv row o=24h+j: j<8 -> q rows (hi/lo) at h*8+j; j<16 -> wkv row h*8+j-8; else wkv row 512+h*8+j-16
__global__ __launch_bounds__(256)
void prep_kernel(const float* __restrict__ wq, const float* __restrict__ wp,
                 const float* __restrict__ gam, const float* __restrict__ bet,
                 const float* __restrict__ mu, const float* __restrict__ va,
                 bf16_t* __restrict__ wqh, bf16_t* __restrict__ wql,
                 bf16_t* __restrict__ wkv, bf16_t* __restrict__ wpb,
                 float* __restrict__ bni, float* __restrict__ bna) {
  const int i = blockIdx.x * 256 + threadIdx.x;
  if (i < 1536 * 512) {
    const int o = i >> 9, col = i & 511;
    const int h = o / 24, j = o % 24;
    const float v = wq[i];
    if (j < 8) {
      const int r = h * 8 + j;
      const bf16_t hi = (bf16_t)v;
      wqh[r * 512 + col] = hi;
      wql[r * 512 + col] = (bf16_t)(v - (float)hi);
    } else if (j < 16) {
      wkv[(size_t)(h * 8 + j - 8) * 512 + col] = (bf16_t)v;
    } else {
      wkv[(size_t)(512 + h * 8 + j - 16) * 512 + col] = (bf16_t)v;
    }
  }
  const int j = i - 1536 * 512;
  if (j >= 0 && j < 512 * 1024) wpb[j] = (bf16_t)wp[j];
  const int k = i - (1536 * 512 + 512 * 1024);
  if (k >= 0 && k < 512) {
    float inv = gam[k] / sqrtf(va[k] + 1e-5f);
    bni[k] = inv;
    bna[k] = bet[k] - mu[k] * inv;
  }
}

// ---------------- K1q: 3-term split GEMM: C_f32 = (Ah+Al)*(Bh+Bl)^T (ll dropped) ----------------
__global__ __launch_bounds__(256, 2)
void gemm_q3_kernel(const bf16_t* __restrict__ Ah, const bf16_t* __restrict__ Al,
                    const bf16_t* __restrict__ Bh, const bf16_t* __restrict__ Bl,
                    float* __restrict__ C, const int M, const int N, const int K) {
  __shared__ __align__(16) bf16_t AsH[128 * 32];
  __shared__ __align__(16) bf16_t AsL[128 * 32];
  __shared__ __align__(16) bf16_t BsH[128 * 32];
  __shared__ __align__(16) bf16_t BsL[128 * 32];
  const int tid  = threadIdx.x;
  const int m0   = blockIdx.y * 128, n0 = blockIdx.x * 128;
  const int wid  = tid >> 6;
  const int lane = tid & 63;
  const int fr   = lane & 15, fg = lane >> 4;
  const int wm   = (wid >> 1) * 64, wn = (wid & 1) * 64;
  const size_t aoff = (size_t)m0 * K, boff = (size_t)n0 * K;
  const int srow = tid >> 2;
  const int soff = (tid & 3) * 8;
  bf16_t* lAH = AsH + (size_t)wid * 16 * 32;
  bf16_t* lAL = AsL + (size_t)wid * 16 * 32;
  bf16_t* lBH = BsH + (size_t)wid * 16 * 32;
  bf16_t* lBL = BsL + (size_t)wid * 16 * 32;

  f32x4 acc[4][4] = {};

  for (int kk = 0; kk < K; kk += 32) {
    __syncthreads();
    const size_t g0 = (size_t)srow * K + kk + soff;
    const size_t g1 = (size_t)(srow + 64) * K + kk + soff;
    gload16(Ah + aoff + g0, lAH);
    gload16(Ah + aoff + g1, lAH + 64 * 32);
    gload16(Al + aoff + g0, lAL);
    gload16(Al + aoff + g1, lAL + 64 * 32);
    gload16(Bh + boff + g0, lBH);
    gload16(Bh + boff + g1, lBH + 64 * 32);
    gload16(Bl + boff + g0, lBL);
    gload16(Bl + boff + g1, lBL + 64 * 32);
    __syncthreads();
    bf16x8 ah[4], al[4], bh[4], bl[4];
#pragma unroll
    for (int i = 0; i < 4; ++i) {
      const int ra = (wm + i * 16 + fr) * 32 + fg * 8;
      ah[i] = *(const bf16x8*)&AsH[ra];
      al[i] = *(const bf16x8*)&AsL[ra];
      const int rb = (wn + i * 16 + fr) * 32 + fg * 8;
      bh[i] = *(const bf16x8*)&BsH[rb];
      bl[i] = *(const bf16x8*)&BsL[rb];
    }
#pragma unroll
    for (int i = 0; i < 4; ++i)
#pragma unroll
      for (int j = 0; j < 4; ++j) {
        acc[i][j] = __builtin_amdgcn_mfma_f32_16x16x32_bf16(ah[i], bh[j], acc[i][j], 0, 0, 0);
        acc[i][j] = __builtin_amdgcn_mfma_f32_16x16x32_bf16(ah[i], bl[j], acc[i][j], 0, 0, 0);
        acc[i][j] = __builtin_amdgcn_mfma_f32_16x16x32_bf16(al[i], bh[j], acc[i][j], 0, 0, 0);
      }
  }

#pragma unroll
  for (int i = 0; i < 4; ++i)
#pragma unroll
    for (int r = 0; r < 4; ++r) {
      const int m = m0 + wm + i * 16 + fg * 4 + r;
#pragma unroll
      for (int j = 0; j < 4; ++j)
        C[(size_t)m * N + n0 + wn + j * 16 + fr] = acc[i][j][r];
    }
}

// ---------------- plain bf16 GEMM: C = A[M][K]*B[N][K]^T (bf16 or f32+BN out) ----------------
template <bool EPI_BN, bool OUT_BF16>
__global__ __launch_bounds__(256, 2)
void gemm_bt_kernel(const bf16_t* __restrict__ A, const bf16_t* __restrict__ B,
                    void* __restrict__ Cout, const int M, const int N, const int K,
                    const float* __restrict__ bni, const float* __restrict__ bna) {
  __shared__ __align__(16) bf16_t As[128 * 32];
  __shared__ __align__(16) bf16_t Bs[128 * 32];
  const int tid  = threadIdx.x;
  const int m0   = blockIdx.y * 128, n0 = blockIdx.x * 128;
  const int wid  = tid >> 6;
  const int lane = tid & 63;
  const int fr   = lane & 15, fg = lane >> 4;
  const int wm   = (wid >> 1) * 64, wn = (wid & 1) * 64;
  const bf16_t* Ab = A + (size_t)m0 * K;
  const bf16_t* Bb = B + (size_t)n0 * K;
  const int srow = tid >> 2;
  const int soff = (tid & 3) * 8;
  bf16_t* lA = As + (size_t)wid * 16 * 32;
  bf16_t* lB = Bs + (size_t)wid * 16 * 32;

  f32x4 acc[4][4] = {};

  for (int kk = 0; kk < K; kk += 32) {
    __syncthreads();
    gload16(Ab + (size_t)srow * K + kk + soff,        lA);
    gload16(Ab + (size_t)(srow + 64) * K + kk + soff, lA + 64 * 32);
    gload16(Bb + (size_t)srow * K + kk + soff,        lB);
    gload16(Bb + (size_t)(srow + 64) * K + kk + soff, lB + 64 * 32);
    __syncthreads();
    bf16x8 af[4], bfr[4];
#pragma unroll
    for (int i = 0; i < 4; ++i) af[i]  = *(const bf16x8*)&As[(wm + i * 16 + fr) * 32 + fg * 8];
#pragma unroll
    for (int j = 0; j < 4; ++j) bfr[j] = *(const bf16x8*)&Bs[(wn + j * 16 + fr) * 32 + fg * 8];
#pragma unroll
    for (int i = 0; i < 4; ++i)
#pragma unroll
      for (int j = 0; j < 4; ++j)
        acc[i][j] = __builtin_amdgcn_mfma_f32_16x16x32_bf16(af[i], bfr[j], acc[i][j], 0, 0, 0);
  }

#pragma unroll
  for (int i = 0; i < 4; ++i)
#pragma unroll
    for (int r = 0; r < 4; ++r) {
      const int m = m0 + wm + i * 16 + fg * 4 + r;
      float sc = 1.f, sh = 0.f;
      if constexpr (EPI_BN) { sc = bni[m]; sh = bna[m]; }
#pragma unroll
      for (int j = 0; j < 4; ++j) {
        const int n = n0 + wn + j * 16 + fr;
        float v = acc[i][j][r];
        if constexpr (EPI_BN) v = v * sc + sh;
        if constexpr (OUT_BF16) ((bf16_t*)Cout)[(size_t)m * N + n] = (bf16_t)v;
        else                    ((float*)Cout)[(size_t)m * N + n] = v;
      }
    }
}

// ---------------- K2: fused dw 5x5 (pad 2) + grouped 1x1; Q from f32 plane, K/V from bf16 plane ----------------
// group g (0..191): typ = g%3 (0:q,1:k,2:v), head = g/3. Output y channel 8g+oc (interleaved).
// LDS tile bf16 [8][36][40], cols = global tx0-4 .. tx0+35.
__global__ __launch_bounds__(256)
void dwpw_kernel(const float* __restrict__ Qf, const bf16_t* __restrict__ KV,
                 const float* __restrict__ wdw, const float* __restrict__ wpw,
                 bf16_t* __restrict__ y) {
  const int g = blockIdx.y, t = blockIdx.x;
  const int typ = g % 3, head = g / 3;
  const int ty0 = (t >> 2) * 32, tx0 = (t & 3) * 32;
  const int tid = threadIdx.x;
  __shared__ __align__(16) bf16_t sin_[8][36][40];
  __shared__ float swd[8][25];
  __shared__ float swp[8][8];
  if (tid < 200) swd[tid / 25][tid % 25] = wdw[(g * 8 + tid / 25) * 25 + tid % 25];
  if (tid < 64)  swp[tid >> 3][tid & 7] = wpw[(g * 8 + (tid >> 3)) * 8 + (tid & 7)];
  const int rbase = (typ == 2 ? 512 : 0) + head * 8;  // row base within Qf (typ0) or KV (typ1/2)
  // stage: 288 (ch,row) tasks; each stages one 40-col row
  for (int task = tid; task < 288; task += 256) {
    const int ch = task / 36, row = task % 36;
    const int iy = ty0 + row - 2;
    const bool rowok = (unsigned)iy < 128u;
    if (typ == 0) {
      const float* src = Qf + (size_t)(head * 8 + ch) * N_PIX + iy * 128;
#pragma unroll
      for (int j = 0; j < 10; ++j) {
        bf16x4 o4;
        if (rowok && !(tx0 == 0 && j == 0) && !(tx0 == 96 && j == 9)) {
          f32x4 v4 = *(const f32x4*)&src[tx0 - 4 + 4 * j];
          o4[0] = (bf16_t)v4[0]; o4[1] = (bf16_t)v4[1];
          o4[2] = (bf16_t)v4[2]; o4[3] = (bf16_t)v4[3];
        } else {
          o4[0] = o4[1] = o4[2] = o4[3] = (bf16_t)0.f;
        }
        *(bf16x4*)&sin_[ch][row][4 * j] = o4;
      }
    } else {
      const bf16_t* src = KV + (size_t)(rbase + ch) * N_PIX + iy * 128;
      bf16x8 v[6];
#pragma unroll
      for (int j = 0; j < 6; ++j) {
        if (rowok && !(tx0 == 0 && j == 0) && !(tx0 == 96 && j == 5))
          v[j] = *(const bf16x8*)&src[tx0 - 8 + 8 * j];
        else
          v[j] = bf16x8{};
      }
      // dest vec4 d (LDS cols 4d..4d+3) <- v[(d+1)>>1] elems (d even ? 4..7 : 0..3)
#pragma unroll
      for (int d = 0; d < 10; ++d) {
        const int j = (d + 1) >> 1;
        bf16x4 o4;
        if ((d & 1) == 0) { o4[0] = v[j][4]; o4[1] = v[j][5]; o4[2] = v[j][6]; o4[3] = v[j][7]; }
        else              { o4[0] = v[j][0]; o4[1] = v[j][1]; o4[2] = v[j][2]; o4[3] = v[j][3]; }
        *(bf16x4*)&sin_[ch][row][4 * d] = o4;
      }
    }
  }
  __syncthreads();
  const int px = (tid & 7) * 4, py = tid >> 3;  // 4 horizontal pixels per thread
  float dwres[8][4];
#pragma unroll
  for (int ch = 0; ch < 8; ++ch) {
    float o0 = 0.f, o1 = 0.f, o2 = 0.f, o3 = 0.f;
#pragma unroll
    for (int di = 0; di < 5; ++di) {
      bf16x4 a0 = *(const bf16x4*)&sin_[ch][py + di][px];
      bf16x4 a1 = *(const bf16x4*)&sin_[ch][py + di][px + 4];
      bf16x4 a2 = *(const bf16x4*)&sin_[ch][py + di][px + 8];
      float vv[12] = {(float)a0[0], (float)a0[1], (float)a0[2], (float)a0[3],
                      (float)a1[0], (float)a1[1], (float)a1[2], (float)a1[3],
                      (float)a2[0], (float)a2[1], (float)a2[2], (float)a2[3]};
#pragma unroll
      for (int dj = 0; dj < 5; ++dj) {
        const float w = swd[ch][di * 5 + dj];
        o0 += vv[dj + 2] * w; o1 += vv[dj + 3] * w;
        o2 += vv[dj + 4] * w; o3 += vv[dj + 5] * w;
      }
    }
    dwres[ch][0] = o0; dwres[ch][1] = o1; dwres[ch][2] = o2; dwres[ch][3] = o3;
  }
#pragma unroll
  for (int oc = 0; oc < 8; ++oc) {
    float o[4] = {0.f, 0.f, 0.f, 0.f};
#pragma unroll
    for (int ic = 0; ic < 8; ++ic) {
      const float w = swp[oc][ic];
#pragma unroll
      for (int u = 0; u < 4; ++u) o[u] += dwres[ic][u] * w;
    }
    bf16x4 ov;
#pragma unroll
    for (int u = 0; u < 4; ++u) ov[u] = (bf16_t)o[u];
    *(bf16x4*)&y[(size_t)(8 * g + oc) * N_PIX + (ty0 + py) * 128 + tx0 + px] = ov;
  }
}

// ---------------- K3a: per-slice partial vk[d][e] = sum_n v_d * relu(k_e) (+ k-sum row) ----------------
__global__ __launch_bounds__(256)
void vk_partial_kernel(const bf16_t* __restrict__ KV, const bf16_t* __restrict__ yb,
                       float* __restrict__ part) {
  const int h = blockIdx.y, s = blockIdx.x;  // s: 0..7 pixel slices
  const bf16_t *kb, *vb;
  if (h < 64) {
    kb = KV + (size_t)(h * 8) * N_PIX;
    vb = KV + (size_t)(512 + h * 8) * N_PIX;
  } else {
    kb = yb + (size_t)(24 * (h - 64) + 8) * N_PIX;
    vb = yb + (size_t)(24 * (h - 64) + 16) * N_PIX;
  }
  float a[8][8] = {};
  float ak[8] = {};
  const int p0 = s * 2048 + (int)threadIdx.x * 2;
  for (int it = 0; it < 4; ++it) {
    const int p = p0 + it * 512;
    float k0[8], k1[8], v0[8], v1[8];
#pragma unroll
    for (int e = 0; e < 8; ++e) {
      bf16x2 kk = *(const bf16x2*)&kb[(size_t)e * N_PIX + p];
      k0[e] = fmaxf(0.f, (float)kk[0]); k1[e] = fmaxf(0.f, (float)kk[1]);
    }
#pragma unroll
    for (int d = 0; d < 8; ++d) {
      bf16x2 vv = *(const bf16x2*)&vb[(size_t)d * N_PIX + p];
      v0[d] = (float)vv[0]; v1[d] = (float)vv[1];
    }
#pragma unroll
    for (int d = 0; d < 8; ++d)
#pragma unroll
      for (int e = 0; e < 8; ++e) {
        a[d][e] += v0[d] * k0[e];
        a[d][e] += v1[d] * k1[e];
      }
#pragma unroll
    for (int e = 0; e < 8; ++e) ak[e] += k0[e] + k1[e];
  }
  __shared__ float red[4][72];
  const int lane = threadIdx.x & 63, wid = threadIdx.x >> 6;
#pragma unroll
  for (int i = 0; i < 72; ++i) {
    float v = (i < 64) ? a[i >> 3][i & 7] : ak[i - 64];
    v += __shfl_xor(v, 32); v += __shfl_xor(v, 16); v += __shfl_xor(v, 8);
    v += __shfl_xor(v, 4);  v += __shfl_xor(v, 2);  v += __shfl_xor(v, 1);
    if (lane == 0) red[wid][i] = v;
  }
  __syncthreads();
  if (threadIdx.x < 72) {
    const float sum_ = red[0][threadIdx.x] + red[1][threadIdx.x] + red[2][threadIdx.x] + red[3][threadIdx.x];
    part[((size_t)h * 8 + s) * 72 + threadIdx.x] = sum_;
  }
}

// ---------------- K3b: deterministic reduce of 8 slices ----------------
__global__ __launch_bounds__(128)
void vk_reduce_kernel(const float* __restrict__ part, float* __restrict__ vk) {
  const int h = blockIdx.x;  // 0..127
  const int i = threadIdx.x;
  if (i < 72) {
    float s = 0.f;
#pragma unroll
    for (int t = 0; t < 8; ++t) s += part[((size_t)h * 8 + t) * 72 + i];
    vk[(size_t)h * 72 + i] = s;
  }
}

// ---------------- K4: attention apply -> attT bf16 [N][1024] ----------------
__global__ __launch_bounds__(256)
void attn_kernel(const float* __restrict__ Qf, const bf16_t* __restrict__ yb,
                 const float* __restrict__ vk, bf16_t* __restrict__ attT) {
  const int n0 = blockIdx.x * 32;
  const int tid = threadIdx.x;
  const int px = tid & 31, hl = tid >> 5;  // hl: 0..7
  __shared__ __align__(16) bf16_t att_s[32 * 512];
  __shared__ float vk_s[576];
  for (int grp = 0; grp < 2; ++grp) {
    for (int hg = 0; hg < 8; ++hg) {
      __syncthreads();  // protect vk_s (and att_s on grp switch)
      for (int i = tid; i < 576; i += 256)
        vk_s[i] = vk[((size_t)grp * 64 + hg * 8) * 72 + i];
      __syncthreads();
      const int hh = hg * 8 + hl;  // head within half (0..63)
      float q[8];
      if (grp == 0) {
        const float* plane = Qf + (size_t)(hh * 8) * N_PIX + n0 + px;
#pragma unroll
        for (int e = 0; e < 8; ++e) q[e] = fmaxf(0.f, plane[(size_t)e * N_PIX]);
      } else {
        const bf16_t* plane = yb + (size_t)(24 * hh) * N_PIX + n0 + px;
#pragma unroll
        for (int e = 0; e < 8; ++e) q[e] = fmaxf(0.f, (float)plane[(size_t)e * N_PIX]);
      }
      float den = 1e-15f;
#pragma unroll
      for (int e = 0; e < 8; ++e) den += vk_s[hl * 72 + 64 + e] * q[e];
      const float rden = 1.0f / den;
      bf16x8 r8;
#pragma unroll
      for (int d = 0; d < 8; ++d) {
        float num = 0.f;
#pragma unroll
        for (int e = 0; e < 8; ++e) num += vk_s[hl * 72 + d * 8 + e] * q[e];
        r8[d] = (bf16_t)(num * rden);
      }
      const int chunk = hg * 8 + hl;  // 16B chunk index within half-row
      *(bf16x8*)&att_s[px * 512 + ((chunk ^ (px & 7)) << 3)] = r8;
    }
    __syncthreads();
    bf16_t* dst = attT + (size_t)n0 * 1024 + grp * 512;
    for (int i = tid; i < 2048; i += 256) {
      const int r = i >> 6, cc = i & 63;
      bf16x8 v = *(const bf16x8*)&att_s[r * 512 + (((cc ^ (r & 7))) << 3)];
      *(bf16x8*)&dst[(size_t)r * 1024 + cc * 8] = v;
    }
  }
}

// ---------------- launch ----------------
extern "C" void kernel_launch(void* const* d_in, const int* in_sizes, int n_in,
                              void* d_out, int out_size, void* d_ws, size_t ws_size,
                              hipStream_t stream) {
  if (ws_size < WS_NEEDED) return;  // need ~155 MB scratch
  const float* x      = (const float*)d_in[0];
  const float* w_qkv  = (const float*)d_in[1];
  const float* w_dw   = (const float*)d_in[2];
  const float* w_pw   = (const float*)d_in[3];
  const float* w_proj = (const float*)d_in[4];
  const float* gam    = (const float*)d_in[5];
  const float* bet    = (const float*)d_in[6];
  const float* mu     = (const float*)d_in[7];
  const float* va     = (const float*)d_in[8];

  char* w = (char*)d_ws;
  float*  Qf   = (float*)(w + OFF_Q);
  bf16_t* KV   = (bf16_t*)(w + OFF_KV);
  bf16_t* yb   = (bf16_t*)(w + OFF_Y);
  bf16_t* xTh  = (bf16_t*)(w + OFF_XTH);  // aliased with attT (dead after GEMMs)
  bf16_t* xTl  = (bf16_t*)(w + OFF_XTL);
  bf16_t* attT = (bf16_t*)(w + OFF_ATT);
  bf16_t* wqh  = (bf16_t*)(w + OFF_WQH);
  bf16_t* wql  = (bf16_t*)(w + OFF_WQL);
  bf16_t* wkv  = (bf16_t*)(w + OFF_WKV);
  bf16_t* wpb  = (bf16_t*)(w + OFF_WP);
  float*  vk   = (float*)(w + OFF_VK);
  float*  part = (float*)(w + OFF_VKP);
  float*  bni  = (float*)(w + OFF_BNI);
  float*  bna  = (float*)(w + OFF_BNA);

  dim3 blk(256);
  // weights + BN fold (once)
  prep_kernel<<<dim3((1536 * 512 + 512 * 1024 + 512 + 255) / 256), blk, 0, stream>>>(
      w_qkv, w_proj, gam, bet, mu, va, wqh, wql, wkv, wpb, bni, bna);

  for (int b = 0; b < 2; ++b) {
    const float* xb = x + (size_t)b * 512 * N_PIX;
    float* outb = (float*)d_out + (size_t)b * 512 * N_PIX;
    // K0a: x -> xT hi/lo bf16
    xpose_kernel<<<dim3(512, 16), blk, 0, stream>>>(xb, xTh, xTl);
    // K1q: Q = wq * x (M=512, K=512), 3-term split, f32 out
    gemm_q3_kernel<<<dim3(128, 4), blk, 0, stream>>>(
        wqh, wql, xTh, xTl, Qf, 512, N_PIX, 512);
    // K1kv: KV = wkv * x (M=1024, K=512), plain bf16
    gemm_bt_kernel<false, true><<<dim3(128, 8), blk, 0, stream>>>(
        wkv, xTh, KV, 1024, N_PIX, 512, nullptr, nullptr);
    // K2: fused dw 5x5 + grouped pw -> y (interleaved bf16)
    dwpw_kernel<<<dim3(16, 192), blk, 0, stream>>>(Qf, KV, w_dw, w_pw, yb);
    // K3: vk accumulation (partials, then deterministic reduce)
    vk_partial_kernel<<<dim3(8, 128), blk, 0, stream>>>(KV, yb, part);
    vk_reduce_kernel<<<dim3(128), dim3(128), 0, stream>>>(part, vk);
    // K4: attention apply -> attT
    attn_kernel<<<dim3(512), blk, 0, stream>>>(Qf, yb, vk, attT);
    // K5: out = w_proj * att + BN (M=512, K=1024), f32 out
    gemm_bt_kernel<true, false><<<dim3(128, 4), blk, 0, stream>>>(
        wpb, attT, outb, 512, N_PIX, 1024, bni, bna);
  }
}

// Round 5
// 398.152 us; speedup vs baseline: 1.5724x; 1.1343x over previous
//
#include <hip/hip_runtime.h>

typedef __bf16 bf16_t;
typedef __bf16 bf16x8 __attribute__((ext_vector_type(8)));
typedef __bf16 bf16x4 __attribute__((ext_vector_type(4)));
typedef __bf16 bf16x2 __attribute__((ext_vector_type(2)));
typedef float  f32x4  __attribute__((ext_vector_type(4)));

#define DEVINL __device__ __forceinline__

static constexpr size_t N_PIX = 16384;

// ---------------- per-batch workspace layout (bytes) ----------------
static constexpr size_t OFF_Q   = 0;                                   // Qf f32 [512][N] (exact-ish q for attn)
static constexpr size_t SZ_Q    = (size_t)512 * N_PIX * 4;             // 33.55 MB
static constexpr size_t OFF_QB  = OFF_Q + SZ_Q;                        // Qb bf16 [512][N] (for dwpw)
static constexpr size_t SZ_QB   = (size_t)512 * N_PIX * 2;             // 16.78 MB
static constexpr size_t OFF_KV  = OFF_QB + SZ_QB;                      // KV bf16 [1024][N]: rows 0..511 K, 512..1023 V
static constexpr size_t SZ_KV   = (size_t)1024 * N_PIX * 2;            // 33.55 MB
static constexpr size_t OFF_Y   = OFF_KV + SZ_KV;                      // y bf16 [1536][N] (interleaved 24/head)
static constexpr size_t SZ_Y    = (size_t)1536 * N_PIX * 2;            // 50.33 MB
static constexpr size_t OFF_ATT = OFF_Y + SZ_Y;                        // attT bf16 [N][1024]; xTh/xTl aliased
static constexpr size_t SZ_ATT  = (size_t)N_PIX * 1024 * 2;            // 33.55 MB
static constexpr size_t OFF_XTH = OFF_ATT;                             // xT_hi bf16 [N][512] (dead after qkv GEMM)
static constexpr size_t OFF_XTL = OFF_ATT + (size_t)N_PIX * 512 * 2;   // xT_lo bf16 [N][512]
static constexpr size_t OFF_WQA = OFF_ATT + SZ_ATT;                    // wqA bf16 [512][1536] = [hi|lo|hi]
static constexpr size_t SZ_WQA  = (size_t)512 * 1536 * 2;
static constexpr size_t OFF_WKV = OFF_WQA + SZ_WQA;                    // wkv bf16 [1024][512]
static constexpr size_t SZ_WKV  = (size_t)1024 * 512 * 2;
static constexpr size_t OFF_WP  = OFF_WKV + SZ_WKV;                    // wpb bf16 [512][1024], pre-scaled by bn inv
static constexpr size_t SZ_WP   = (size_t)512 * 1024 * 2;
static constexpr size_t OFF_VK  = OFF_WP + SZ_WP;                      // vk f32 [128][72]
static constexpr size_t SZ_VK   = (size_t)128 * 72 * 4;
static constexpr size_t OFF_VKP = OFF_VK + SZ_VK;                      // vk partials f32 [128][8][72]
static constexpr size_t SZ_VKP  = (size_t)128 * 8 * 72 * 4;
static constexpr size_t OFF_BNA = OFF_VKP + SZ_VKP;                    // f32[512]
static constexpr size_t OFF_ZP  = OFF_BNA + 2048;                      // 64B zero page
static constexpr size_t WS_NEEDED = OFF_ZP + 64;                       // ~171.8 MB

// ---------------- helpers ----------------
DEVINL void gload16(const bf16_t* g, bf16_t* l) {
  // async global->LDS, 16B per lane; LDS dest = wave-uniform base + lane*16, global addr per-lane
  __builtin_amdgcn_global_load_lds((const __attribute__((address_space(1))) void*)g,
                                   (__attribute__((address_space(3))) void*)l, 16, 0, 0);
}

// ---------------- K0a: transpose x (f32 [512][N]) -> xT_hi/xT_lo (bf16 [N][512]) ----------------
__global__ __launch_bounds__(256)
void xpose_kernel(const float* __restrict__ x, bf16_t* __restrict__ xTh, bf16_t* __restrict__ xTl) {
  __shared__ float t[32][33];
  const int n0 = blockIdx.x * 32, c0 = blockIdx.y * 32;
  const int tx = threadIdx.x & 31, ty = threadIdx.x >> 5;  // ty 0..7
#pragma unroll
  for (int r = 0; r < 4; ++r)
    t[ty + r * 8][tx] = x[(size_t)(c0 + ty + r * 8) * N_PIX + n0 + tx];
  __syncthreads();
#pragma unroll
  for (int r = 0; r < 4; ++r) {
    const float v = t[tx][ty + r * 8];
    const bf16_t hi = (bf16_t)v;
    const bf16_t lo = (bf16_t)(v - (float)hi);
    const size_t o = (size_t)(n0 + ty + r * 8) * 512 + c0 + tx;
    xTh[o] = hi; xTl[o] = lo;
  }
}

// ---------------- K0b: build wqA [hi|lo|hi], wkv, scaled wpb, bna, zero page ----------------
static constexpr int PREP_W1 = 512 * 1536;           // wqA
static constexpr int PREP_W2 = 1024 * 512;           // wkv
static constexpr int PREP_W3 = 512 * 1024;           // wpb
static constexpr int PREP_TOT = PREP_W1 + PREP_W2 + PREP_W3 + 512 + 16;
__global__ __launch_bounds__(256)
void prep_kernel(const float* __restrict__ wq, const float* __restrict__ wp,
                 const float* __restrict__ gam, const float* __restrict__ bet,
                 const float* __restrict__ mu, const float* __restrict__ va,
                 bf16_t* __restrict__ wqA, bf16_t* __restrict__ wkv, bf16_t* __restrict__ wpb,
                 float* __restrict__ bna, float* __restrict__ zp) {
  const int i = blockIdx.x * 256 + threadIdx.x;
  if (i < PREP_W1) {
    const int r = i / 1536, c = i - r * 1536;
    const int o = (r >> 3) * 24 + (r & 7);  // q row in original w_qkv
    bf16_t out;
    if (c < 512) {
      out = (bf16_t)wq[o * 512 + c];
    } else if (c < 1024) {
      const float v = wq[o * 512 + c - 512];
      const bf16_t hi = (bf16_t)v;
      out = (bf16_t)(v - (float)hi);
    } else {
      out = (bf16_t)wq[o * 512 + c - 1024];
    }
    wqA[i] = out;
  } else if (i < PREP_W1 + PREP_W2) {
    const int j = i - PREP_W1;
    const int r = j >> 9, c = j & 511;
    const int h = (r & 511) >> 3;
    const int jj = (r < 512 ? 8 : 16) + (r & 7);
    wkv[j] = (bf16_t)wq[(h * 24 + jj) * 512 + c];
  } else if (i < PREP_W1 + PREP_W2 + PREP_W3) {
    const int j = i - PREP_W1 - PREP_W2;
    const int m = j >> 10;
    const float inv = gam[m] / sqrtf(va[m] + 1e-5f);
    wpb[j] = (bf16_t)(wp[j] * inv);
  } else if (i < PREP_W1 + PREP_W2 + PREP_W3 + 512) {
    const int k = i - PREP_W1 - PREP_W2 - PREP_W3;
    const float inv = gam[k] / sqrtf(va[k] + 1e-5f);
    bna[k] = bet[k] - mu[k] * inv;
  } else if (i < PREP_TOT) {
    zp[i - (PREP_W1 + PREP_W2 + PREP_W3 + 512)] = 0.f;
  }
}

// ---------------- K1: merged q/kv GEMM, 128x128 tile, BK=64 ----------------
// by<4: q rows (K=1536 over [wq_hi|wq_lo|wq_hi] x [xTh|xTh|xTl]) -> Qf f32 + Qb bf16
// by>=4: kv rows (K=512, wkv x xTh) -> KV bf16
__global__ __launch_bounds__(256, 2)
void gemm_qkv_kernel(const bf16_t* __restrict__ wqA, const bf16_t* __restrict__ wkv,
                     const bf16_t* __restrict__ xTh, const bf16_t* __restrict__ xTl,
                     float* __restrict__ Qf, bf16_t* __restrict__ Qb, bf16_t* __restrict__ KV) {
  __shared__ __align__(16) bf16_t As[128 * 64];
  __shared__ __align__(16) bf16_t Bs[128 * 64];
  const int tid = threadIdx.x, wid = tid >> 6, lane = tid & 63;
  const int fr = lane & 15, fg = lane >> 4;
  const int wm = (wid >> 1) * 64, wn = (wid & 1) * 64;
  const int by = blockIdx.y;
  const bool isQ = by < 4;
  const int m0 = (isQ ? by : by - 4) * 128;
  const int n0 = blockIdx.x * 128;
  const int KA = isQ ? 1536 : 512;
  const bf16_t* Aptr = isQ ? wqA + (size_t)m0 * 1536 : wkv + (size_t)m0 * 512;
  const int srow = tid >> 3;       // 0..31
  const int soff = (tid & 7) * 8;  // 16B chunk within 64

  f32x4 acc[4][4] = {};

  for (int kk = 0; kk < KA; kk += 64) {
    const bf16_t* Bpl;
    int bcol;
    if (isQ) {
      Bpl  = (kk < 1024) ? xTh : xTl;
      bcol = (kk < 1024) ? (kk & 511) : (kk - 1024);
    } else {
      Bpl = xTh; bcol = kk;
    }
    __syncthreads();  // prev iter's LDS reads done
#pragma unroll
    for (int r = 0; r < 4; ++r) {
      gload16(Aptr + (size_t)(srow + 32 * r) * KA + kk + soff, As + (wid * 8 + 32 * r) * 64);
      gload16(Bpl + (size_t)(n0 + srow + 32 * r) * 512 + bcol + soff, Bs + (wid * 8 + 32 * r) * 64);
    }
    __syncthreads();  // drains vmcnt(0)
#pragma unroll
    for (int ks = 0; ks < 2; ++ks) {
      bf16x8 af[4], bfr[4];
#pragma unroll
      for (int i = 0; i < 4; ++i) af[i]  = *(const bf16x8*)&As[(wm + i * 16 + fr) * 64 + ks * 32 + fg * 8];
#pragma unroll
      for (int j = 0; j < 4; ++j) bfr[j] = *(const bf16x8*)&Bs[(wn + j * 16 + fr) * 64 + ks * 32 + fg * 8];
#pragma unroll
      for (int i = 0; i < 4; ++i)
#pragma unroll
        for (int j = 0; j < 4; ++j)
          acc[i][j] = __builtin_amdgcn_mfma_f32_16x16x32_bf16(af[i], bfr[j], acc[i][j], 0, 0, 0);
    }
  }

#pragma unroll
  for (int i = 0; i < 4; ++i)
#pragma unroll
    for (int r = 0; r < 4; ++r) {
      const int m = m0 + wm + i * 16 + fg * 4 + r;
#pragma unroll
      for (int j = 0; j < 4; ++j) {
        const int n = n0 + wn + j * 16 + fr;
        const float v = acc[i][j][r];
        if (isQ) {
          Qf[(size_t)m * N_PIX + n] = v;
          Qb[(size_t)m * N_PIX + n] = (bf16_t)v;
        } else {
          KV[(size_t)m * N_PIX + n] = (bf16_t)v;
        }
      }
    }
}

// ---------------- K5: proj GEMM (BN folded into A; epilogue +bna), BK=64 ----------------
__global__ __launch_bounds__(256, 2)
void gemm_proj_kernel(const bf16_t* __restrict__ A, const bf16_t* __restrict__ B,
                      float* __restrict__ Cout, const float* __restrict__ bna) {
  __shared__ __align__(16) bf16_t As[128 * 64];
  __shared__ __align__(16) bf16_t Bs[128 * 64];
  const int tid = threadIdx.x, wid = tid >> 6, lane = tid & 63;
  const int fr = lane & 15, fg = lane >> 4;
  const int wm = (wid >> 1) * 64, wn = (wid & 1) * 64;
  const int m0 = blockIdx.y * 128, n0 = blockIdx.x * 128;
  const int srow = tid >> 3;
  const int soff = (tid & 7) * 8;
  const bf16_t* Ab = A + (size_t)m0 * 1024;
  const bf16_t* Bb = B + (size_t)n0 * 1024;

  f32x4 acc[4][4] = {};

  for (int kk = 0; kk < 1024; kk += 64) {
    __syncthreads();
#pragma unroll
    for (int r = 0; r < 4; ++r) {
      gload16(Ab + (size_t)(srow + 32 * r) * 1024 + kk + soff, As + (wid * 8 + 32 * r) * 64);
      gload16(Bb + (size_t)(srow + 32 * r) * 1024 + kk + soff, Bs + (wid * 8 + 32 * r) * 64);
    }
    __syncthreads();
#pragma unroll
    for (int ks = 0; ks < 2; ++ks) {
      bf16x8 af[4], bfr[4];
#pragma unroll
      for (int i = 0; i < 4; ++i) af[i]  = *(const bf16x8*)&As[(wm + i * 16 + fr) * 64 + ks * 32 + fg * 8];
#pragma unroll
      for (int j = 0; j < 4; ++j) bfr[j] = *(const bf16x8*)&Bs[(wn + j * 16 + fr) * 64 + ks * 32 + fg * 8];
#pragma unroll
      for (int i = 0; i < 4; ++i)
#pragma unroll
        for (int j = 0; j < 4; ++j)
          acc[i][j] = __builtin_amdgcn_mfma_f32_16x16x32_bf16(af[i], bfr[j], acc[i][j], 0, 0, 0);
    }
  }

#pragma unroll
  for (int i = 0; i < 4; ++i)
#pragma unroll
    for (int r = 0; r < 4; ++r) {
      const int m = m0 + wm + i * 16 + fg * 4 + r;
      const float sh = bna[m];
#pragma unroll
      for (int j = 0; j < 4; ++j)
        Cout[(size_t)m * N_PIX + n0 + wn + j * 16 + fr] = acc[i][j][r] + sh;
    }
}

// ---------------- K2: fused dw 5x5 (pad 2) + grouped 1x1; all-bf16, DMA-staged ----------------
// group g (0..191): typ=g%3 (0:q from Qb, 1:k, 2:v from KV), head=g/3; tile 16x64 pixels
__global__ __launch_bounds__(256)
void dwpw_kernel(const bf16_t* __restrict__ Qb, const bf16_t* __restrict__ KV,
                 const float* __restrict__ wdw, const float* __restrict__ wpw,
                 const bf16_t* __restrict__ zp, bf16_t* __restrict__ y) {
  const int g = blockIdx.y, t = blockIdx.x;
  const int typ = g % 3, head = g / 3;
  const int ty0 = (t >> 1) * 16, tx0 = (t & 1) * 64;
  const int tid = threadIdx.x, wid = tid >> 6, lane = tid & 63;
  __shared__ __align__(16) bf16_t sin_[8][20][80];  // rows: gy=ty0+row-2; cols: gx=tx0+c-8
  __shared__ float swd[8][25];
  __shared__ float swp[8][8];
  if (tid < 200) swd[tid / 25][tid % 25] = wdw[(g * 8 + tid / 25) * 25 + tid % 25];
  if (tid < 64)  swp[tid >> 3][tid & 7] = wpw[(g * 8 + (tid >> 3)) * 8 + (tid & 7)];
  const bf16_t* plane = (typ == 0) ? (Qb + (size_t)head * 8 * N_PIX)
                                   : (KV + (size_t)((typ == 2 ? 512 : 0) + head * 8) * N_PIX);
  bf16_t* sflat = &sin_[0][0][0];
  // 1600 16B chunks: chunk id -> [ch][row][c6*8..+7]; OOB lanes read the zero page
  for (int base = wid * 64; base < 1600; base += 256) {
    const int id  = base + lane;
    const int ch  = id / 200;
    const int rem = id - ch * 200;
    const int row = rem / 10;
    const int c6  = rem - row * 10;
    const int gy  = ty0 + row - 2;
    const int gx  = tx0 + c6 * 8 - 8;
    const bool ok = ((unsigned)gy < 128u) && ((unsigned)gx < 128u);
    const bf16_t* src = ok ? (plane + (size_t)ch * N_PIX + gy * 128 + gx) : zp;
    gload16(src, sflat + (size_t)base * 8);
  }
  __syncthreads();  // drains DMA (vmcnt 0) + weight loads

  const int px4 = (tid & 15) * 4, py = tid >> 4;  // 4 horizontal pixels per thread, 16 rows
  float dwres[8][4];
#pragma unroll
  for (int ch = 0; ch < 8; ++ch) {
    float o0 = 0.f, o1 = 0.f, o2 = 0.f, o3 = 0.f;
#pragma unroll
    for (int di = 0; di < 5; ++di) {
      bf16x4 a0 = *(const bf16x4*)&sin_[ch][py + di][px4 + 4];
      bf16x4 a1 = *(const bf16x4*)&sin_[ch][py + di][px4 + 8];
      bf16x4 a2 = *(const bf16x4*)&sin_[ch][py + di][px4 + 12];
      float vv[12] = {(float)a0[0], (float)a0[1], (float)a0[2], (float)a0[3],
                      (float)a1[0], (float)a1[1], (float)a1[2], (float)a1[3],
                      (float)a2[0], (float)a2[1], (float)a2[2], (float)a2[3]};
#pragma unroll
      for (int dj = 0; dj < 5; ++dj) {
        const float w = swd[ch][di * 5 + dj];
        o0 += vv[dj + 2] * w; o1 += vv[dj + 3] * w;
        o2 += vv[dj + 4] * w; o3 += vv[dj + 5] * w;
      }
    }
    dwres[ch][0] = o0; dwres[ch][1] = o1; dwres[ch][2] = o2; dwres[ch][3] = o3;
  }
#pragma unroll
  for (int oc = 0; oc < 8; ++oc) {
    float o[4] = {0.f, 0.f, 0.f, 0.f};
#pragma unroll
    for (int ic = 0; ic < 8; ++ic) {
      const float w = swp[oc][ic];
#pragma unroll
      for (int u = 0; u < 4; ++u) o[u] += dwres[ic][u] * w;
    }
    bf16x4 ov;
#pragma unroll
    for (int u = 0; u < 4; ++u) ov[u] = (bf16_t)o[u];
    *(bf16x4*)&y[(size_t)(8 * g + oc) * N_PIX + (ty0 + py) * 128 + tx0 + px4] = ov;
  }
}

// ---------------- K3a: per-slice partial vk[d][e] = sum_n v_d * relu(k_e) (+ k-sum row) ----------------
__global__ __launch_bounds__(256)
void vk_partial_kernel(const bf16_t* __restrict__ KV, const bf16_t* __restrict__ yb,
                       float* __restrict__ part) {
  const int h = blockIdx.y, s = blockIdx.x;  // s: 0..7 pixel slices
  const bf16_t *kb, *vb;
  if (h < 64) {
    kb = KV + (size_t)(h * 8) * N_PIX;
    vb = KV + (size_t)(512 + h * 8) * N_PIX;
  } else {
    kb = yb + (size_t)(24 * (h - 64) + 8) * N_PIX;
    vb = yb + (size_t)(24 * (h - 64) + 16) * N_PIX;
  }
  float a[8][8] = {};
  float ak[8] = {};
  const int p0 = s * 2048 + (int)threadIdx.x * 2;
  for (int it = 0; it < 4; ++it) {
    const int p = p0 + it * 512;
    float k0[8], k1[8], v0[8], v1[8];
#pragma unroll
    for (int e = 0; e < 8; ++e) {
      bf16x2 kk = *(const bf16x2*)&kb[(size_t)e * N_PIX + p];
      k0[e] = fmaxf(0.f, (float)kk[0]); k1[e] = fmaxf(0.f, (float)kk[1]);
    }
#pragma unroll
    for (int d = 0; d < 8; ++d) {
      bf16x2 vv = *(const bf16x2*)&vb[(size_t)d * N_PIX + p];
      v0[d] = (float)vv[0]; v1[d] = (float)vv[1];
    }
#pragma unroll
    for (int d = 0; d < 8; ++d)
#pragma unroll
      for (int e = 0; e < 8; ++e) {
        a[d][e] += v0[d] * k0[e];
        a[d][e] += v1[d] * k1[e];
      }
#pragma unroll
    for (int e = 0; e < 8; ++e) ak[e] += k0[e] + k1[e];
  }
  __shared__ float red[4][72];
  const int lane = threadIdx.x & 63, wid = threadIdx.x >> 6;
#pragma unroll
  for (int i = 0; i < 72; ++i) {
    float v = (i < 64) ? a[i >> 3][i & 7] : ak[i - 64];
    v += __shfl_xor(v, 32); v += __shfl_xor(v, 16); v += __shfl_xor(v, 8);
    v += __shfl_xor(v, 4);  v += __shfl_xor(v, 2);  v += __shfl_xor(v, 1);
    if (lane == 0) red[wid][i] = v;
  }
  __syncthreads();
  if (threadIdx.x < 72) {
    const float sum_ = red[0][threadIdx.x] + red[1][threadIdx.x] + red[2][threadIdx.x] + red[3][threadIdx.x];
    part[((size_t)h * 8 + s) * 72 + threadIdx.x] = sum_;
  }
}

// ---------------- K3b: deterministic reduce of 8 slices ----------------
__global__ __launch_bounds__(128)
void vk_reduce_kernel(const float* __restrict__ part, float* __restrict__ vk) {
  const int h = blockIdx.x;  // 0..127
  const int i = threadIdx.x;
  if (i < 72) {
    float s = 0.f;
#pragma unroll
    for (int t = 0; t < 8; ++t) s += part[((size_t)h * 8 + t) * 72 + i];
    vk[(size_t)h * 72 + i] = s;
  }
}

// ---------------- K4: attention apply -> attT bf16 [N][1024] ----------------
__global__ __launch_bounds__(256)
void attn_kernel(const float* __restrict__ Qf, const bf16_t* __restrict__ yb,
                 const float* __restrict__ vk, bf16_t* __restrict__ attT) {
  const int n0 = blockIdx.x * 32;
  const int tid = threadIdx.x;
  const int px = tid & 31, hl = tid >> 5;  // hl: 0..7
  __shared__ __align__(16) bf16_t att_s[32 * 512];
  __shared__ float vk_s[576];
  for (int grp = 0; grp < 2; ++grp) {
    for (int hg = 0; hg < 8; ++hg) {
      __syncthreads();  // protect vk_s (and att_s on grp switch)
      for (int i = tid; i < 576; i += 256)
        vk_s[i] = vk[((size_t)grp * 64 + hg * 8) * 72 + i];
      __syncthreads();
      const int hh = hg * 8 + hl;  // head within half (0..63)
      float q[8];
      if (grp == 0) {
        const float* plane = Qf + (size_t)(hh * 8) * N_PIX + n0 + px;
#pragma unroll
        for (int e = 0; e < 8; ++e) q[e] = fmaxf(0.f, plane[(size_t)e * N_PIX]);
      } else {
        const bf16_t* plane = yb + (size_t)(24 * hh) * N_PIX + n0 + px;
#pragma unroll
        for (int e = 0; e < 8; ++e) q[e] = fmaxf(0.f, (float)plane[(size_t)e * N_PIX]);
      }
      float den = 1e-15f;
#pragma unroll
      for (int e = 0; e < 8; ++e) den += vk_s[hl * 72 + 64 + e] * q[e];
      const float rden = 1.0f / den;
      bf16x8 r8;
#pragma unroll
      for (int d = 0; d < 8; ++d) {
        float num = 0.f;
#pragma unroll
        for (int e = 0; e < 8; ++e) num += vk_s[hl * 72 + d * 8 + e] * q[e];
        r8[d] = (bf16_t)(num * rden);
      }
      const int chunk = hg * 8 + hl;  // 16B chunk index within half-row
      *(bf16x8*)&att_s[px * 512 + ((chunk ^ (px & 7)) << 3)] = r8;
    }
    __syncthreads();
    bf16_t* dst = attT + (size_t)n0 * 1024 + grp * 512;
    for (int i = tid; i < 2048; i += 256) {
      const int r = i >> 6, cc = i & 63;
      bf16x8 v = *(const bf16x8*)&att_s[r * 512 + (((cc ^ (r & 7))) << 3)];
      *(bf16x8*)&dst[(size_t)r * 1024 + cc * 8] = v;
    }
  }
}

// ---------------- launch ----------------
extern "C" void kernel_launch(void* const* d_in, const int* in_sizes, int n_in,
                              void* d_out, int out_size, void* d_ws, size_t ws_size,
                              hipStream_t stream) {
  if (ws_size < WS_NEEDED) return;  // need ~172 MB scratch
  const float* x      = (const float*)d_in[0];
  const float* w_qkv  = (const float*)d_in[1];
  const float* w_dw   = (const float*)d_in[2];
  const float* w_pw   = (const float*)d_in[3];
  const float* w_proj = (const float*)d_in[4];
  const float* gam    = (const float*)d_in[5];
  const float* bet    = (const float*)d_in[6];
  const float* mu     = (const float*)d_in[7];
  const float* va     = (const float*)d_in[8];

  char* w = (char*)d_ws;
  float*  Qf   = (float*)(w + OFF_Q);
  bf16_t* Qb   = (bf16_t*)(w + OFF_QB);
  bf16_t* KV   = (bf16_t*)(w + OFF_KV);
  bf16_t* yb   = (bf16_t*)(w + OFF_Y);
  bf16_t* xTh  = (bf16_t*)(w + OFF_XTH);  // aliased with attT (dead after K1)
  bf16_t* xTl  = (bf16_t*)(w + OFF_XTL);
  bf16_t* attT = (bf16_t*)(w + OFF_ATT);
  bf16_t* wqA  = (bf16_t*)(w + OFF_WQA);
  bf16_t* wkv  = (bf16_t*)(w + OFF_WKV);
  bf16_t* wpb  = (bf16_t*)(w + OFF_WP);
  float*  vk   = (float*)(w + OFF_VK);
  float*  part = (float*)(w + OFF_VKP);
  float*  bna  = (float*)(w + OFF_BNA);
  float*  zp   = (float*)(w + OFF_ZP);

  dim3 blk(256);
  // weights + BN fold + zero page (once)
  prep_kernel<<<dim3((PREP_TOT + 255) / 256), blk, 0, stream>>>(
      w_qkv, w_proj, gam, bet, mu, va, wqA, wkv, wpb, bna, zp);

  for (int b = 0; b < 2; ++b) {
    const float* xb = x + (size_t)b * 512 * N_PIX;
    float* outb = (float*)d_out + (size_t)b * 512 * N_PIX;
    // K0a: x -> xT hi/lo bf16
    xpose_kernel<<<dim3(512, 16), blk, 0, stream>>>(xb, xTh, xTl);
    // K1: merged q (3-term via K=1536) + kv GEMM
    gemm_qkv_kernel<<<dim3(128, 12), blk, 0, stream>>>(wqA, wkv, xTh, xTl, Qf, Qb, KV);
    // K2: fused dw 5x5 + grouped pw -> y (interleaved bf16)
    dwpw_kernel<<<dim3(16, 192), blk, 0, stream>>>(Qb, KV, w_dw, w_pw, (const bf16_t*)zp, yb);
    // K3: vk accumulation (partials, then deterministic reduce)
    vk_partial_kernel<<<dim3(8, 128), blk, 0, stream>>>(KV, yb, part);
    vk_reduce_kernel<<<dim3(128), dim3(128), 0, stream>>>(part, vk);
    // K4: attention apply -> attT
    attn_kernel<<<dim3(512), blk, 0, stream>>>(Qf, yb, vk, attT);
    // K5: out = wpb * att + bna (M=512, K=1024), f32 out
    gemm_proj_kernel<<<dim3(128, 4), blk, 0, stream>>>(wpb, attT, outb, bna);
  }
}

// Round 6
// 380.391 us; speedup vs baseline: 1.6458x; 1.0467x over previous
//
#include <hip/hip_runtime.h>

typedef __bf16 bf16_t;
typedef __bf16 bf16x8 __attribute__((ext_vector_type(8)));
typedef __bf16 bf16x4 __attribute__((ext_vector_type(4)));
typedef __bf16 bf16x2 __attribute__((ext_vector_type(2)));
typedef float  f32x4  __attribute__((ext_vector_type(4)));

#define DEVINL __device__ __forceinline__

static constexpr size_t N_PIX = 16384;

// ---------------- per-batch workspace layout (bytes) ----------------
static constexpr size_t OFF_Q   = 0;                                   // Qf f32 [512][N] (exact-ish q for attn)
static constexpr size_t SZ_Q    = (size_t)512 * N_PIX * 4;             // 33.55 MB
static constexpr size_t OFF_QB  = OFF_Q + SZ_Q;                        // Qb bf16 [512][N] (for dwpw)
static constexpr size_t SZ_QB   = (size_t)512 * N_PIX * 2;             // 16.78 MB
static constexpr size_t OFF_KV  = OFF_QB + SZ_QB;                      // KV bf16 [1024][N]: rows 0..511 K, 512..1023 V
static constexpr size_t SZ_KV   = (size_t)1024 * N_PIX * 2;            // 33.55 MB
static constexpr size_t OFF_Y   = OFF_KV + SZ_KV;                      // y bf16 [1536][N] (interleaved 24/head)
static constexpr size_t SZ_Y    = (size_t)1536 * N_PIX * 2;            // 50.33 MB
static constexpr size_t OFF_ATT = OFF_Y + SZ_Y;                        // attT bf16 [N][1024]; xTh/xTl aliased
static constexpr size_t SZ_ATT  = (size_t)N_PIX * 1024 * 2;            // 33.55 MB
static constexpr size_t OFF_XTH = OFF_ATT;                             // xT_hi bf16 [N][512] (dead after qkv GEMM)
static constexpr size_t OFF_XTL = OFF_ATT + (size_t)N_PIX * 512 * 2;   // xT_lo bf16 [N][512]
static constexpr size_t OFF_WQA = OFF_ATT + SZ_ATT;                    // wqA bf16 [512][1536] = [hi|lo|hi]
static constexpr size_t SZ_WQA  = (size_t)512 * 1536 * 2;
static constexpr size_t OFF_WKV = OFF_WQA + SZ_WQA;                    // wkv bf16 [1024][512]
static constexpr size_t SZ_WKV  = (size_t)1024 * 512 * 2;
static constexpr size_t OFF_WP  = OFF_WKV + SZ_WKV;                    // wpb bf16 [512][1024], pre-scaled by bn inv
static constexpr size_t SZ_WP   = (size_t)512 * 1024 * 2;
static constexpr size_t OFF_VK  = OFF_WP + SZ_WP;                      // vk f32 [128][72]
static constexpr size_t SZ_VK   = (size_t)128 * 72 * 4;
static constexpr size_t OFF_VKP = OFF_VK + SZ_VK;                      // vk partials f32 [128][8][72]
static constexpr size_t SZ_VKP  = (size_t)128 * 8 * 72 * 4;
static constexpr size_t OFF_BNA = OFF_VKP + SZ_VKP;                    // f32[512]
static constexpr size_t OFF_ZP  = OFF_BNA + 2048;                      // 64B zero page
static constexpr size_t WS_NEEDED = OFF_ZP + 64;                       // ~171.8 MB

// ---------------- helpers ----------------
DEVINL void gload16(const bf16_t* g, bf16_t* l) {
  // async global->LDS, 16B per lane; LDS dest = wave-uniform base + lane*16, global addr per-lane
  __builtin_amdgcn_global_load_lds((const __attribute__((address_space(1))) void*)g,
                                   (__attribute__((address_space(3))) void*)l, 16, 0, 0);
}

// ---------------- K0a: transpose x (f32 [512][N]) -> xT_hi/xT_lo (bf16 [N][512]) ----------------
__global__ __launch_bounds__(256)
void xpose_kernel(const float* __restrict__ x, bf16_t* __restrict__ xTh, bf16_t* __restrict__ xTl) {
  __shared__ float t[32][33];
  const int n0 = blockIdx.x * 32, c0 = blockIdx.y * 32;
  const int tx = threadIdx.x & 31, ty = threadIdx.x >> 5;  // ty 0..7
#pragma unroll
  for (int r = 0; r < 4; ++r)
    t[ty + r * 8][tx] = x[(size_t)(c0 + ty + r * 8) * N_PIX + n0 + tx];
  __syncthreads();
#pragma unroll
  for (int r = 0; r < 4; ++r) {
    const float v = t[tx][ty + r * 8];
    const bf16_t hi = (bf16_t)v;
    const bf16_t lo = (bf16_t)(v - (float)hi);
    const size_t o = (size_t)(n0 + ty + r * 8) * 512 + c0 + tx;
    xTh[o] = hi; xTl[o] = lo;
  }
}

// ---------------- K0b: build wqA [hi|lo|hi], wkv, scaled wpb, bna, zero page ----------------
static constexpr int PREP_W1 = 512 * 1536;           // wqA
static constexpr int PREP_W2 = 1024 * 512;           // wkv
static constexpr int PREP_W3 = 512 * 1024;           // wpb
static constexpr int PREP_TOT = PREP_W1 + PREP_W2 + PREP_W3 + 512 + 16;
__global__ __launch_bounds__(256)
void prep_kernel(const float* __restrict__ wq, const float* __restrict__ wp,
                 const float* __restrict__ gam, const float* __restrict__ bet,
                 const float* __restrict__ mu, const float* __restrict__ va,
                 bf16_t* __restrict__ wqA, bf16_t* __restrict__ wkv, bf16_t* __restrict__ wpb,
                 float* __restrict__ bna, float* __restrict__ zp) {
  const int i = blockIdx.x * 256 + threadIdx.x;
  if (i < PREP_W1) {
    const int r = i / 1536, c = i - r * 1536;
    const int o = (r >> 3) * 24 + (r & 7);  // q row in original w_qkv
    bf16_t out;
    if (c < 512) {
      out = (bf16_t)wq[o * 512 + c];
    } else if (c < 1024) {
      const float v = wq[o * 512 + c - 512];
      const bf16_t hi = (bf16_t)v;
      out = (bf16_t)(v - (float)hi);
    } else {
      out = (bf16_t)wq[o * 512 + c - 1024];
    }
    wqA[i] = out;
  } else if (i < PREP_W1 + PREP_W2) {
    const int j = i - PREP_W1;
    const int r = j >> 9, c = j & 511;
    const int h = (r & 511) >> 3;
    const int jj = (r < 512 ? 8 : 16) + (r & 7);
    wkv[j] = (bf16_t)wq[(h * 24 + jj) * 512 + c];
  } else if (i < PREP_W1 + PREP_W2 + PREP_W3) {
    const int j = i - PREP_W1 - PREP_W2;
    const int m = j >> 10;
    const float inv = gam[m] / sqrtf(va[m] + 1e-5f);
    wpb[j] = (bf16_t)(wp[j] * inv);
  } else if (i < PREP_W1 + PREP_W2 + PREP_W3 + 512) {
    const int k = i - PREP_W1 - PREP_W2 - PREP_W3;
    const float inv = gam[k] / sqrtf(va[k] + 1e-5f);
    bna[k] = bet[k] - mu[k] * inv;
  } else if (i < PREP_TOT) {
    zp[i - (PREP_W1 + PREP_W2 + PREP_W3 + 512)] = 0.f;
  }
}

// ---------------- K1: merged q/kv GEMM, 128x128 tile, BK=64, XOR-swizzled LDS ----------------
// by<4: q rows (K=1536 over [wq_hi|wq_lo|wq_hi] x [xTh|xTh|xTl]) -> Qf f32 + Qb bf16
// by>=4: kv rows (K=512, wkv x xTh) -> KV bf16
// swizzle: LDS chunk c of row r holds logical chunk c^(r&7); gload src pre-swizzled, reads swizzled.
__global__ __launch_bounds__(256, 4)
void gemm_qkv_kernel(const bf16_t* __restrict__ wqA, const bf16_t* __restrict__ wkv,
                     const bf16_t* __restrict__ xTh, const bf16_t* __restrict__ xTl,
                     float* __restrict__ Qf, bf16_t* __restrict__ Qb, bf16_t* __restrict__ KV) {
  __shared__ __align__(16) bf16_t As[128 * 64];
  __shared__ __align__(16) bf16_t Bs[128 * 64];
  const int tid = threadIdx.x, wid = tid >> 6, lane = tid & 63;
  const int fr = lane & 15, fg = lane >> 4;
  const int wm = (wid >> 1) * 64, wn = (wid & 1) * 64;
  const int by = blockIdx.y;
  const bool isQ = by < 4;
  const int m0 = (isQ ? by : by - 4) * 128;
  const int n0 = blockIdx.x * 128;
  const int KA = isQ ? 1536 : 512;
  const bf16_t* Aptr = isQ ? wqA + (size_t)m0 * 1536 : wkv + (size_t)m0 * 512;
  const int srow = tid >> 3;                              // 0..31 (LDS row mod 32)
  const int soff = (((tid & 7) ^ (srow & 7)) * 8);        // pre-swizzled global chunk

  f32x4 acc[4][4] = {};

  for (int kk = 0; kk < KA; kk += 64) {
    const bf16_t* Bpl;
    int bcol;
    if (isQ) {
      Bpl  = (kk < 1024) ? xTh : xTl;
      bcol = (kk < 1024) ? (kk & 511) : (kk - 1024);
    } else {
      Bpl = xTh; bcol = kk;
    }
    __syncthreads();  // prev iter's LDS reads done
#pragma unroll
    for (int r = 0; r < 4; ++r) {
      gload16(Aptr + (size_t)(srow + 32 * r) * KA + kk + soff, As + (wid * 8 + 32 * r) * 64);
      gload16(Bpl + (size_t)(n0 + srow + 32 * r) * 512 + bcol + soff, Bs + (wid * 8 + 32 * r) * 64);
    }
    __syncthreads();  // drains vmcnt(0)
#pragma unroll
    for (int ks = 0; ks < 2; ++ks) {
      bf16x8 af[4], bfr[4];
#pragma unroll
      for (int i = 0; i < 4; ++i)
        af[i]  = *(const bf16x8*)&As[(wm + i * 16 + fr) * 64 + (((ks * 4 + fg) ^ (fr & 7)) * 8)];
#pragma unroll
      for (int j = 0; j < 4; ++j)
        bfr[j] = *(const bf16x8*)&Bs[(wn + j * 16 + fr) * 64 + (((ks * 4 + fg) ^ (fr & 7)) * 8)];
#pragma unroll
      for (int i = 0; i < 4; ++i)
#pragma unroll
        for (int j = 0; j < 4; ++j)
          acc[i][j] = __builtin_amdgcn_mfma_f32_16x16x32_bf16(af[i], bfr[j], acc[i][j], 0, 0, 0);
    }
  }

#pragma unroll
  for (int i = 0; i < 4; ++i)
#pragma unroll
    for (int r = 0; r < 4; ++r) {
      const int m = m0 + wm + i * 16 + fg * 4 + r;
#pragma unroll
      for (int j = 0; j < 4; ++j) {
        const int n = n0 + wn + j * 16 + fr;
        const float v = acc[i][j][r];
        if (isQ) {
          Qf[(size_t)m * N_PIX + n] = v;
          Qb[(size_t)m * N_PIX + n] = (bf16_t)v;
        } else {
          KV[(size_t)m * N_PIX + n] = (bf16_t)v;
        }
      }
    }
}

// ---------------- K5: proj GEMM (BN folded into A; epilogue +bna), BK=64, swizzled ----------------
__global__ __launch_bounds__(256, 4)
void gemm_proj_kernel(const bf16_t* __restrict__ A, const bf16_t* __restrict__ B,
                      float* __restrict__ Cout, const float* __restrict__ bna) {
  __shared__ __align__(16) bf16_t As[128 * 64];
  __shared__ __align__(16) bf16_t Bs[128 * 64];
  const int tid = threadIdx.x, wid = tid >> 6, lane = tid & 63;
  const int fr = lane & 15, fg = lane >> 4;
  const int wm = (wid >> 1) * 64, wn = (wid & 1) * 64;
  const int m0 = blockIdx.y * 128, n0 = blockIdx.x * 128;
  const int srow = tid >> 3;
  const int soff = (((tid & 7) ^ (srow & 7)) * 8);
  const bf16_t* Ab = A + (size_t)m0 * 1024;
  const bf16_t* Bb = B + (size_t)n0 * 1024;

  f32x4 acc[4][4] = {};

  for (int kk = 0; kk < 1024; kk += 64) {
    __syncthreads();
#pragma unroll
    for (int r = 0; r < 4; ++r) {
      gload16(Ab + (size_t)(srow + 32 * r) * 1024 + kk + soff, As + (wid * 8 + 32 * r) * 64);
      gload16(Bb + (size_t)(srow + 32 * r) * 1024 + kk + soff, Bs + (wid * 8 + 32 * r) * 64);
    }
    __syncthreads();
#pragma unroll
    for (int ks = 0; ks < 2; ++ks) {
      bf16x8 af[4], bfr[4];
#pragma unroll
      for (int i = 0; i < 4; ++i)
        af[i]  = *(const bf16x8*)&As[(wm + i * 16 + fr) * 64 + (((ks * 4 + fg) ^ (fr & 7)) * 8)];
#pragma unroll
      for (int j = 0; j < 4; ++j)
        bfr[j] = *(const bf16x8*)&Bs[(wn + j * 16 + fr) * 64 + (((ks * 4 + fg) ^ (fr & 7)) * 8)];
#pragma unroll
      for (int i = 0; i < 4; ++i)
#pragma unroll
        for (int j = 0; j < 4; ++j)
          acc[i][j] = __builtin_amdgcn_mfma_f32_16x16x32_bf16(af[i], bfr[j], acc[i][j], 0, 0, 0);
    }
  }

#pragma unroll
  for (int i = 0; i < 4; ++i)
#pragma unroll
    for (int r = 0; r < 4; ++r) {
      const int m = m0 + wm + i * 16 + fg * 4 + r;
      const float sh = bna[m];
#pragma unroll
      for (int j = 0; j < 4; ++j)
        Cout[(size_t)m * N_PIX + n0 + wn + j * 16 + fr] = acc[i][j][r] + sh;
    }
}

// ---------------- K2: fused dw 5x5 (pad 2) + grouped 1x1; all-bf16, DMA-staged ----------------
// group g (0..191): typ=g%3 (0:q from Qb, 1:k, 2:v from KV), head=g/3; tile 16x64 pixels
__global__ __launch_bounds__(256)
void dwpw_kernel(const bf16_t* __restrict__ Qb, const bf16_t* __restrict__ KV,
                 const float* __restrict__ wdw, const float* __restrict__ wpw,
                 const bf16_t* __restrict__ zp, bf16_t* __restrict__ y) {
  const int g = blockIdx.y, t = blockIdx.x;
  const int typ = g % 3, head = g / 3;
  const int ty0 = (t >> 1) * 16, tx0 = (t & 1) * 64;
  const int tid = threadIdx.x, wid = tid >> 6, lane = tid & 63;
  __shared__ __align__(16) bf16_t sin_[8][20][80];  // rows: gy=ty0+row-2; cols: gx=tx0+c-8
  __shared__ float swd[8][25];
  __shared__ float swp[8][8];
  if (tid < 200) swd[tid / 25][tid % 25] = wdw[(g * 8 + tid / 25) * 25 + tid % 25];
  if (tid < 64)  swp[tid >> 3][tid & 7] = wpw[(g * 8 + (tid >> 3)) * 8 + (tid & 7)];
  const bf16_t* plane = (typ == 0) ? (Qb + (size_t)head * 8 * N_PIX)
                                   : (KV + (size_t)((typ == 2 ? 512 : 0) + head * 8) * N_PIX);
  bf16_t* sflat = &sin_[0][0][0];
  // 1600 16B chunks: chunk id -> [ch][row][c6*8..+7]; OOB lanes read the zero page
  for (int base = wid * 64; base < 1600; base += 256) {
    const int id  = base + lane;
    const int ch  = id / 200;
    const int rem = id - ch * 200;
    const int row = rem / 10;
    const int c6  = rem - row * 10;
    const int gy  = ty0 + row - 2;
    const int gx  = tx0 + c6 * 8 - 8;
    const bool ok = ((unsigned)gy < 128u) && ((unsigned)gx < 128u);
    const bf16_t* src = ok ? (plane + (size_t)ch * N_PIX + gy * 128 + gx) : zp;
    gload16(src, sflat + (size_t)base * 8);
  }
  __syncthreads();  // drains DMA (vmcnt 0) + weight loads

  const int px4 = (tid & 15) * 4, py = tid >> 4;  // 4 horizontal pixels per thread, 16 rows
  float dwres[8][4];
#pragma unroll
  for (int ch = 0; ch < 8; ++ch) {
    float o0 = 0.f, o1 = 0.f, o2 = 0.f, o3 = 0.f;
#pragma unroll
    for (int di = 0; di < 5; ++di) {
      bf16x4 a0 = *(const bf16x4*)&sin_[ch][py + di][px4 + 4];
      bf16x4 a1 = *(const bf16x4*)&sin_[ch][py + di][px4 + 8];
      bf16x4 a2 = *(const bf16x4*)&sin_[ch][py + di][px4 + 12];
      float vv[12] = {(float)a0[0], (float)a0[1], (float)a0[2], (float)a0[3],
                      (float)a1[0], (float)a1[1], (float)a1[2], (float)a1[3],
                      (float)a2[0], (float)a2[1], (float)a2[2], (float)a2[3]};
#pragma unroll
      for (int dj = 0; dj < 5; ++dj) {
        const float w = swd[ch][di * 5 + dj];
        o0 += vv[dj + 2] * w; o1 += vv[dj + 3] * w;
        o2 += vv[dj + 4] * w; o3 += vv[dj + 5] * w;
      }
    }
    dwres[ch][0] = o0; dwres[ch][1] = o1; dwres[ch][2] = o2; dwres[ch][3] = o3;
  }
#pragma unroll
  for (int oc = 0; oc < 8; ++oc) {
    float o[4] = {0.f, 0.f, 0.f, 0.f};
#pragma unroll
    for (int ic = 0; ic < 8; ++ic) {
      const float w = swp[oc][ic];
#pragma unroll
      for (int u = 0; u < 4; ++u) o[u] += dwres[ic][u] * w;
    }
    bf16x4 ov;
#pragma unroll
    for (int u = 0; u < 4; ++u) ov[u] = (bf16_t)o[u];
    *(bf16x4*)&y[(size_t)(8 * g + oc) * N_PIX + (ty0 + py) * 128 + tx0 + px4] = ov;
  }
}

// ---------------- K3a: per-slice partial vk[d][e] = sum_n v_d * relu(k_e) (+ k-sum row) ----------------
__global__ __launch_bounds__(256)
void vk_partial_kernel(const bf16_t* __restrict__ KV, const bf16_t* __restrict__ yb,
                       float* __restrict__ part) {
  const int h = blockIdx.y, s = blockIdx.x;  // s: 0..7 pixel slices
  const bf16_t *kb, *vb;
  if (h < 64) {
    kb = KV + (size_t)(h * 8) * N_PIX;
    vb = KV + (size_t)(512 + h * 8) * N_PIX;
  } else {
    kb = yb + (size_t)(24 * (h - 64) + 8) * N_PIX;
    vb = yb + (size_t)(24 * (h - 64) + 16) * N_PIX;
  }
  float a[8][8] = {};
  float ak[8] = {};
  const int p0 = s * 2048 + (int)threadIdx.x * 2;
  for (int it = 0; it < 4; ++it) {
    const int p = p0 + it * 512;
    float k0[8], k1[8], v0[8], v1[8];
#pragma unroll
    for (int e = 0; e < 8; ++e) {
      bf16x2 kk = *(const bf16x2*)&kb[(size_t)e * N_PIX + p];
      k0[e] = fmaxf(0.f, (float)kk[0]); k1[e] = fmaxf(0.f, (float)kk[1]);
    }
#pragma unroll
    for (int d = 0; d < 8; ++d) {
      bf16x2 vv = *(const bf16x2*)&vb[(size_t)d * N_PIX + p];
      v0[d] = (float)vv[0]; v1[d] = (float)vv[1];
    }
#pragma unroll
    for (int d = 0; d < 8; ++d)
#pragma unroll
      for (int e = 0; e < 8; ++e) {
        a[d][e] += v0[d] * k0[e];
        a[d][e] += v1[d] * k1[e];
      }
#pragma unroll
    for (int e = 0; e < 8; ++e) ak[e] += k0[e] + k1[e];
  }
  __shared__ float red[4][72];
  const int lane = threadIdx.x & 63, wid = threadIdx.x >> 6;
#pragma unroll
  for (int i = 0; i < 72; ++i) {
    float v = (i < 64) ? a[i >> 3][i & 7] : ak[i - 64];
    v += __shfl_xor(v, 32); v += __shfl_xor(v, 16); v += __shfl_xor(v, 8);
    v += __shfl_xor(v, 4);  v += __shfl_xor(v, 2);  v += __shfl_xor(v, 1);
    if (lane == 0) red[wid][i] = v;
  }
  __syncthreads();
  if (threadIdx.x < 72) {
    const float sum_ = red[0][threadIdx.x] + red[1][threadIdx.x] + red[2][threadIdx.x] + red[3][threadIdx.x];
    part[((size_t)h * 8 + s) * 72 + threadIdx.x] = sum_;
  }
}

// ---------------- K3b: deterministic reduce of 8 slices ----------------
__global__ __launch_bounds__(128)
void vk_reduce_kernel(const float* __restrict__ part, float* __restrict__ vk) {
  const int h = blockIdx.x;  // 0..127
  const int i = threadIdx.x;
  if (i < 72) {
    float s = 0.f;
#pragma unroll
    for (int t = 0; t < 8; ++t) s += part[((size_t)h * 8 + t) * 72 + i];
    vk[(size_t)h * 72 + i] = s;
  }
}

// ---------------- K4: attention apply -> attT bf16 [N][1024] ----------------
__global__ __launch_bounds__(256)
void attn_kernel(const float* __restrict__ Qf, const bf16_t* __restrict__ yb,
                 const float* __restrict__ vk, bf16_t* __restrict__ attT) {
  const int n0 = blockIdx.x * 32;
  const int tid = threadIdx.x;
  const int px = tid & 31, hl = tid >> 5;  // hl: 0..7
  __shared__ __align__(16) bf16_t att_s[32 * 512];
  __shared__ float vk_s[576];
  for (int grp = 0; grp < 2; ++grp) {
    for (int hg = 0; hg < 8; ++hg) {
      __syncthreads();  // protect vk_s (and att_s on grp switch)
      for (int i = tid; i < 576; i += 256)
        vk_s[i] = vk[((size_t)grp * 64 + hg * 8) * 72 + i];
      __syncthreads();
      const int hh = hg * 8 + hl;  // head within half (0..63)
      float q[8];
      if (grp == 0) {
        const float* plane = Qf + (size_t)(hh * 8) * N_PIX + n0 + px;
#pragma unroll
        for (int e = 0; e < 8; ++e) q[e] = fmaxf(0.f, plane[(size_t)e * N_PIX]);
      } else {
        const bf16_t* plane = yb + (size_t)(24 * hh) * N_PIX + n0 + px;
#pragma unroll
        for (int e = 0; e < 8; ++e) q[e] = fmaxf(0.f, (float)plane[(size_t)e * N_PIX]);
      }
      float den = 1e-15f;
#pragma unroll
      for (int e = 0; e < 8; ++e) den += vk_s[hl * 72 + 64 + e] * q[e];
      const float rden = 1.0f / den;
      bf16x8 r8;
#pragma unroll
      for (int d = 0; d < 8; ++d) {
        float num = 0.f;
#pragma unroll
        for (int e = 0; e < 8; ++e) num += vk_s[hl * 72 + d * 8 + e] * q[e];
        r8[d] = (bf16_t)(num * rden);
      }
      const int chunk = hg * 8 + hl;  // 16B chunk index within half-row
      *(bf16x8*)&att_s[px * 512 + ((chunk ^ (px & 7)) << 3)] = r8;
    }
    __syncthreads();
    bf16_t* dst = attT + (size_t)n0 * 1024 + grp * 512;
    for (int i = tid; i < 2048; i += 256) {
      const int r = i >> 6, cc = i & 63;
      bf16x8 v = *(const bf16x8*)&att_s[r * 512 + (((cc ^ (r & 7))) << 3)];
      *(bf16x8*)&dst[(size_t)r * 1024 + cc * 8] = v;
    }
  }
}

// ---------------- launch ----------------
extern "C" void kernel_launch(void* const* d_in, const int* in_sizes, int n_in,
                              void* d_out, int out_size, void* d_ws, size_t ws_size,
                              hipStream_t stream) {
  if (ws_size < WS_NEEDED) return;  // need ~172 MB scratch
  const float* x      = (const float*)d_in[0];
  const float* w_qkv  = (const float*)d_in[1];
  const float* w_dw   = (const float*)d_in[2];
  const float* w_pw   = (const float*)d_in[3];
  const float* w_proj = (const float*)d_in[4];
  const float* gam    = (const float*)d_in[5];
  const float* bet    = (const float*)d_in[6];
  const float* mu     = (const float*)d_in[7];
  const float* va     = (const float*)d_in[8];

  char* w = (char*)d_ws;
  float*  Qf   = (float*)(w + OFF_Q);
  bf16_t* Qb   = (bf16_t*)(w + OFF_QB);
  bf16_t* KV   = (bf16_t*)(w + OFF_KV);
  bf16_t* yb   = (bf16_t*)(w + OFF_Y);
  bf16_t* xTh  = (bf16_t*)(w + OFF_XTH);  // aliased with attT (dead after K1)
  bf16_t* xTl  = (bf16_t*)(w + OFF_XTL);
  bf16_t* attT = (bf16_t*)(w + OFF_ATT);
  bf16_t* wqA  = (bf16_t*)(w + OFF_WQA);
  bf16_t* wkv  = (bf16_t*)(w + OFF_WKV);
  bf16_t* wpb  = (bf16_t*)(w + OFF_WP);
  float*  vk   = (float*)(w + OFF_VK);
  float*  part = (float*)(w + OFF_VKP);
  float*  bna  = (float*)(w + OFF_BNA);
  float*  zp   = (float*)(w + OFF_ZP);

  dim3 blk(256);
  // weights + BN fold + zero page (once)
  prep_kernel<<<dim3((PREP_TOT + 255) / 256), blk, 0, stream>>>(
      w_qkv, w_proj, gam, bet, mu, va, wqA, wkv, wpb, bna, zp);

  for (int b = 0; b < 2; ++b) {
    const float* xb = x + (size_t)b * 512 * N_PIX;
    float* outb = (float*)d_out + (size_t)b * 512 * N_PIX;
    // K0a: x -> xT hi/lo bf16
    xpose_kernel<<<dim3(512, 16), blk, 0, stream>>>(xb, xTh, xTl);
    // K1: merged q (3-term via K=1536) + kv GEMM
    gemm_qkv_kernel<<<dim3(128, 12), blk, 0, stream>>>(wqA, wkv, xTh, xTl, Qf, Qb, KV);
    // K2: fused dw 5x5 + grouped pw -> y (interleaved bf16)
    dwpw_kernel<<<dim3(16, 192), blk, 0, stream>>>(Qb, KV, w_dw, w_pw, (const bf16_t*)zp, yb);
    // K3: vk accumulation (partials, then deterministic reduce)
    vk_partial_kernel<<<dim3(8, 128), blk, 0, stream>>>(KV, yb, part);
    vk_reduce_kernel<<<dim3(128), dim3(128), 0, stream>>>(part, vk);
    // K4: attention apply -> attT
    attn_kernel<<<dim3(512), blk, 0, stream>>>(Qf, yb, vk, attT);
    // K5: out = wpb * att + bna (M=512, K=1024), f32 out
    gemm_proj_kernel<<<dim3(128, 4), blk, 0, stream>>>(wpb, attT, outb, bna);
  }
}